// Round 7
// baseline (752.660 us; speedup 1.0000x reference)
//
#include <hip/hip_runtime.h>
#include <math.h>

#define NN 131072            // total nodes
#define FF 32                // input features
#define EE 524288            // random edges
#define ET (EE + NN)         // edges + self loops = 655360
#define BB 2048              // batch (graphs)

// ---------------- wave reductions (wave64) ----------------
__device__ __forceinline__ float wave_sum(float v) {
  #pragma unroll
  for (int o = 32; o >= 1; o >>= 1) v += __shfl_xor(v, o);
  return v;
}
__device__ __forceinline__ float wave_max(float v) {
  #pragma unroll
  for (int o = 32; o >= 1; o >>= 1) v = fmaxf(v, __shfl_xor(v, o));
  return v;
}

// ---------------- CSR build (counting sort by dst) ----------------
__global__ void init_counts(int* counts) {
  int i = blockIdx.x * 256 + threadIdx.x;
  counts[i] = 1;                       // self loop contributes 1 per node
}

__global__ void count_edges(const int* __restrict__ ei, int* counts) {
  int e = blockIdx.x * 256 + threadIdx.x;
  atomicAdd(&counts[ei[EE + e]], 1);   // dst row of edge_index
}

__global__ void scan_block(const int* __restrict__ counts, int* offs, int* blksums) {
  __shared__ int sd[256];
  int t = threadIdx.x;
  int i = blockIdx.x * 256 + t;
  int v = counts[i];
  sd[t] = v;
  __syncthreads();
  for (int o = 1; o < 256; o <<= 1) {
    int x = (t >= o) ? sd[t - o] : 0;
    __syncthreads();
    sd[t] += x;
    __syncthreads();
  }
  offs[i] = sd[t] - v;                 // block-local exclusive scan
  if (t == 255) blksums[blockIdx.x] = sd[255];
}

__global__ void scan_sums(int* blksums) {  // 1 block x 512 threads
  __shared__ int sd[512];
  int t = threadIdx.x;
  int v = blksums[t];
  sd[t] = v;
  __syncthreads();
  for (int o = 1; o < 512; o <<= 1) {
    int x = (t >= o) ? sd[t - o] : 0;
    __syncthreads();
    sd[t] += x;
    __syncthreads();
  }
  blksums[t] = sd[t] - v;              // exclusive scan of block sums
}

__global__ void scan_add(int* offs, int* cursor, const int* __restrict__ blksums) {
  int i = blockIdx.x * 256 + threadIdx.x;
  int o = offs[i] + blksums[blockIdx.x];
  offs[i] = o;
  cursor[i] = o;
  if (i == 0) offs[NN] = ET;
}

__global__ void fill_csr(const int* __restrict__ ei, int* cursor, int* esrc) {
  int i = blockIdx.x * 256 + threadIdx.x;   // i < ET
  int s, d;
  if (i < EE) { s = ei[i]; d = ei[EE + i]; }
  else        { s = d = i - EE; }           // self loop
  int pos = atomicAdd(&cursor[d], 1);
  esrc[pos] = s;
}

// ---------------- layer-1 attention vectors: wts[h,k] = sum_c W1[k,h*64+c]*a1s[h,c]
__global__ void l1_avec(const float* __restrict__ W1, const float* __restrict__ a1s,
                        const float* __restrict__ a1d, float* __restrict__ wts,
                        float* __restrict__ wtd) {
  int t = threadIdx.x;          // 128 threads: h = t>>5, k = t&31
  int h = t >> 5, k = t & 31;
  float as = 0.f, ad = 0.f;
  #pragma unroll
  for (int c = 0; c < 64; ++c) {
    float w = W1[k * 256 + h * 64 + c];
    as += w * a1s[h * 64 + c];
    ad += w * a1d[h * 64 + c];
  }
  wts[t] = as;
  wtd[t] = ad;
}

// ---------------- layer-1 logits: als[n,h] = x[n]·wts[h]  (64 nodes / block)
__global__ __launch_bounds__(256) void l1_logits(
    const float* __restrict__ x, const float* __restrict__ wts,
    const float* __restrict__ wtd, float* __restrict__ als, float* __restrict__ ald) {
  __shared__ float sx[64 * 33];     // padded stride 33: kill bank conflicts
  __shared__ float sts[128], std_[128];
  int t = threadIdx.x;
  int n0 = blockIdx.x * 64;
  #pragma unroll
  for (int j = 0; j < 8; ++j) {
    int idx = t + j * 256;          // 0..2047
    sx[(idx >> 5) * 33 + (idx & 31)] = x[(size_t)n0 * 32 + idx];
  }
  if (t < 128) sts[t] = wts[t]; else std_[t - 128] = wtd[t - 128];
  __syncthreads();
  int nl = t >> 2, h = t & 3;       // 64 nodes x 4 heads
  float vs = 0.f, vd = 0.f;
  #pragma unroll
  for (int k = 0; k < 32; ++k) {
    float xv = sx[nl * 33 + k];
    vs += xv * sts[h * 32 + k];
    vd += xv * std_[h * 32 + k];
  }
  als[(n0 + nl) * 4 + h] = vs;
  ald[(n0 + nl) * 4 + h] = vd;
}

// ---------------- fused GAT1 v2: one wave per node, heads in registers.
// Phase A (lane=edge): float4 als gather -> 4 head logits, online (M,S) x4.
// Phase B (lane = feature k + 32*parity): x[src] gathered ONCE, 4 head FMAs;
//   per-edge (src,p0..p3) fetched via __shfl with 1-deep prefetch.
// Epilogue: agg1[n,h*64+c] = relu(xa[h]·W1[:,h*64+c] + b1).
__global__ __launch_bounds__(256) void gat1_fused(
    const float* __restrict__ x, const float* __restrict__ als,
    const float* __restrict__ ald, const int* __restrict__ offs,
    const int* __restrict__ esrc, const float* __restrict__ W1,
    const float* __restrict__ b1, float* __restrict__ agg1) {
  __shared__ float sW1[32 * 256];   // 32 KB, whole W1
  __shared__ float sxa[4][128];     // [wave][h*32+k]
  int t = threadIdx.x;
  #pragma unroll
  for (int j = 0; j < 32; ++j) sW1[t + j * 256] = W1[t + j * 256];
  __syncthreads();
  int wv = t >> 6, lane = t & 63;
  int k = lane & 31, jp = lane >> 5;
  int n = blockIdx.x * 4 + wv;
  int start = offs[n], end = offs[n + 1];
  float4 ad4 = *(const float4*)&ald[n * 4];
  float M0 = -INFINITY, M1 = -INFINITY, M2 = -INFINITY, M3 = -INFINITY;
  float S0 = 0.f, S1 = 0.f, S2 = 0.f, S3 = 0.f;
  float xa0 = 0.f, xa1 = 0.f, xa2 = 0.f, xa3 = 0.f;
  for (int j0 = start; j0 < end; j0 += 64) {
    int cnt = end - j0; if (cnt > 64) cnt = 64;
    // phase A: lane = edge
    int s = 0;
    float e0 = -INFINITY, e1 = -INFINITY, e2 = -INFINITY, e3 = -INFINITY;
    if (lane < cnt) {
      s = esrc[j0 + lane];
      float4 a4 = *(const float4*)&als[s * 4];
      e0 = a4.x + ad4.x; e0 = (e0 > 0.f) ? e0 : 0.2f * e0;
      e1 = a4.y + ad4.y; e1 = (e1 > 0.f) ? e1 : 0.2f * e1;
      e2 = a4.z + ad4.z; e2 = (e2 > 0.f) ? e2 : 0.2f * e2;
      e3 = a4.w + ad4.w; e3 = (e3 > 0.f) ? e3 : 0.2f * e3;
    }
    float Mn0 = fmaxf(M0, wave_max(e0));
    float Mn1 = fmaxf(M1, wave_max(e1));
    float Mn2 = fmaxf(M2, wave_max(e2));
    float Mn3 = fmaxf(M3, wave_max(e3));
    float sc0 = __expf(M0 - Mn0), sc1 = __expf(M1 - Mn1);
    float sc2 = __expf(M2 - Mn2), sc3 = __expf(M3 - Mn3);
    float p0 = (lane < cnt) ? __expf(e0 - Mn0) : 0.f;
    float p1 = (lane < cnt) ? __expf(e1 - Mn1) : 0.f;
    float p2 = (lane < cnt) ? __expf(e2 - Mn2) : 0.f;
    float p3 = (lane < cnt) ? __expf(e3 - Mn3) : 0.f;
    S0 = S0 * sc0 + wave_sum(p0);
    S1 = S1 * sc1 + wave_sum(p1);
    S2 = S2 * sc2 + wave_sum(p2);
    S3 = S3 * sc3 + wave_sum(p3);
    xa0 *= sc0; xa1 *= sc1; xa2 *= sc2; xa3 *= sc3;
    M0 = Mn0; M1 = Mn1; M2 = Mn2; M3 = Mn3;
    // phase B: lane = (k, parity jp); edges jp, jp+2, ... via shfl w/ prefetch
    int jj = jp;
    int sj = __shfl(s, jj & 63);
    float q0 = __shfl(p0, jj & 63), q1 = __shfl(p1, jj & 63);
    float q2 = __shfl(p2, jj & 63), q3 = __shfl(p3, jj & 63);
    while (jj < cnt) {
      int jn = jj + 2;
      int sn = __shfl(s, jn & 63);
      float r0 = __shfl(p0, jn & 63), r1 = __shfl(p1, jn & 63);
      float r2 = __shfl(p2, jn & 63), r3 = __shfl(p3, jn & 63);
      float xv = x[(size_t)sj * 32 + k];
      xa0 += q0 * xv; xa1 += q1 * xv; xa2 += q2 * xv; xa3 += q3 * xv;
      sj = sn; q0 = r0; q1 = r1; q2 = r2; q3 = r3;
      jj = jn;
    }
  }
  // combine the two edge-parities
  xa0 += __shfl_xor(xa0, 32);
  xa1 += __shfl_xor(xa1, 32);
  xa2 += __shfl_xor(xa2, 32);
  xa3 += __shfl_xor(xa3, 32);
  sxa[wv][0 * 32 + k] = xa0 / (S0 + 1e-16f);
  sxa[wv][1 * 32 + k] = xa1 / (S1 + 1e-16f);
  sxa[wv][2 * 32 + k] = xa2 / (S2 + 1e-16f);
  sxa[wv][3 * 32 + k] = xa3 / (S3 + 1e-16f);   // wave-local: no barrier
  #pragma unroll
  for (int hh = 0; hh < 4; ++hh) {
    float acc = b1[hh * 64 + lane];
    #pragma unroll
    for (int kq = 0; kq < 8; ++kq) {
      float4 a4 = *(const float4*)&sxa[wv][hh * 32 + kq * 4];
      acc += a4.x * sW1[(kq * 4 + 0) * 256 + hh * 64 + lane];
      acc += a4.y * sW1[(kq * 4 + 1) * 256 + hh * 64 + lane];
      acc += a4.z * sW1[(kq * 4 + 2) * 256 + hh * 64 + lane];
      acc += a4.w * sW1[(kq * 4 + 3) * 256 + hh * 64 + lane];
    }
    agg1[(size_t)n * 256 + hh * 64 + lane] = fmaxf(acc, 0.f);
  }
}

// ---------------- float4 register-tiled GEMM: A[M,K] @ W[K,64]
template <int KTILES, int ROWS, bool AL>
__global__ __launch_bounds__(256) void gemm_n64(
    const float* __restrict__ A, const float* __restrict__ W,
    const float* __restrict__ bias, const float* __restrict__ a_s,
    const float* __restrict__ a_d, float* __restrict__ out,
    float* __restrict__ als, float* __restrict__ ald) {
  constexpr int K = KTILES * 64;
  constexpr int RPT = ROWS / 16;       // rows per thread
  constexpr int SAS = 68;              // sA stride: 16B-aligned, bank-staggered
  __shared__ float sW[64 * 64];        // [k][c] 16 KB
  __shared__ float sA[ROWS * SAS];
  int t = threadIdx.x;
  int cq = t & 15;
  int rs = t >> 4;
  int row0 = blockIdx.x * ROWS;
  float4 acc[RPT];
  #pragma unroll
  for (int rp = 0; rp < RPT; ++rp) acc[rp] = make_float4(0.f, 0.f, 0.f, 0.f);
  for (int kt = 0; kt < KTILES; ++kt) {
    #pragma unroll
    for (int j = 0; j < 4; ++j) {      // stage W tile [64][64]
      int li = t + j * 256;
      int kk = li >> 4, cc = (li & 15) * 4;
      *(float4*)&sW[kk * 64 + cc] =
          *(const float4*)&W[(size_t)(kt * 64 + kk) * 64 + cc];
    }
    #pragma unroll
    for (int j = 0; j < ROWS / 16; ++j) {  // stage A tile [ROWS][64]
      int li = t + j * 256;
      int r = li >> 4, kkq = (li & 15) * 4;
      *(float4*)&sA[r * SAS + kkq] =
          *(const float4*)&A[(size_t)(row0 + r) * K + kt * 64 + kkq];
    }
    __syncthreads();
    #pragma unroll
    for (int kq = 0; kq < 16; ++kq) {
      float4 a4[RPT];
      #pragma unroll
      for (int rp = 0; rp < RPT; ++rp)
        a4[rp] = *(const float4*)&sA[(rs * RPT + rp) * SAS + kq * 4];
      #pragma unroll
      for (int i = 0; i < 4; ++i) {
        float4 w4 = *(const float4*)&sW[(kq * 4 + i) * 64 + cq * 4];
        #pragma unroll
        for (int rp = 0; rp < RPT; ++rp) {
          float a = (i == 0) ? a4[rp].x : (i == 1) ? a4[rp].y
                  : (i == 2) ? a4[rp].z : a4[rp].w;
          acc[rp].x += a * w4.x; acc[rp].y += a * w4.y;
          acc[rp].z += a * w4.z; acc[rp].w += a * w4.w;
        }
      }
    }
    __syncthreads();
  }
  #pragma unroll
  for (int rp = 0; rp < RPT; ++rp) {
    int r = row0 + rs * RPT + rp;
    if constexpr (AL) {
      *(float4*)&out[(size_t)r * 64 + cq * 4] = acc[rp];   // raw h
      float4 s4 = *(const float4*)&a_s[cq * 4];
      float4 d4 = *(const float4*)&a_d[cq * 4];
      float vs = acc[rp].x * s4.x + acc[rp].y * s4.y + acc[rp].z * s4.z + acc[rp].w * s4.w;
      float vd = acc[rp].x * d4.x + acc[rp].y * d4.y + acc[rp].z * d4.z + acc[rp].w * d4.w;
      #pragma unroll
      for (int o = 8; o >= 1; o >>= 1) { vs += __shfl_xor(vs, o); vd += __shfl_xor(vd, o); }
      if (cq == 0) { als[r] = vs; ald[r] = vd; }
    } else {
      float4 b4 = *(const float4*)&bias[cq * 4];
      float4 v = acc[rp];
      v.x = fmaxf(v.x + b4.x, 0.f); v.y = fmaxf(v.y + b4.y, 0.f);
      v.z = fmaxf(v.z + b4.z, 0.f); v.w = fmaxf(v.w + b4.w, 0.f);
      *(float4*)&out[(size_t)r * 64 + cq * 4] = v;
    }
  }
}

// ---------------- layer-2 aggregate fused with W3 GEMM + als3/ald3 epilogue
__global__ __launch_bounds__(256) void gat_agg_w3(
    const float* __restrict__ hsrc, const float* __restrict__ als,
    const float* __restrict__ ald, const int* __restrict__ offs,
    const int* __restrict__ esrc, const float* __restrict__ bias,
    const float* __restrict__ W3, const float* __restrict__ a3s,
    const float* __restrict__ a3d, float* __restrict__ hout,
    float* __restrict__ als3, float* __restrict__ ald3) {
  __shared__ float sW3[64 * 64];   // 16 KB
  __shared__ float lp[4][64];
  __shared__ int   lsrc[4][64];
  __shared__ float srow[4][64];
  int t = threadIdx.x;
  #pragma unroll
  for (int j = 0; j < 4; ++j) {
    int li = t + j * 256;
    int kk = li >> 4, cc = (li & 15) * 4;
    *(float4*)&sW3[kk * 64 + cc] = *(const float4*)&W3[kk * 64 + cc];
  }
  __syncthreads();
  int wv = t >> 6, lane = t & 63;
  int n = blockIdx.x * 4 + wv;
  int start = offs[n], end = offs[n + 1];
  float aldn = ald[n];
  float M = -INFINITY, S = 0.f, acc = 0.f;
  for (int j0 = start; j0 < end; j0 += 64) {
    int cnt = end - j0; if (cnt > 64) cnt = 64;
    int s = 0; float e = -INFINITY;
    if (lane < cnt) {
      s = esrc[j0 + lane];
      e = als[s] + aldn;
      e = (e > 0.f) ? e : 0.2f * e;               // leaky relu
    }
    float Mn = fmaxf(M, wave_max(e));             // self-loop => cnt>=1
    float scale = __expf(M - Mn);                 // first chunk: exp(-inf)=0
    float p = (lane < cnt) ? __expf(e - Mn) : 0.f;
    S = S * scale + wave_sum(p);
    acc *= scale;
    lp[wv][lane] = p;
    lsrc[wv][lane] = s;                           // wave-local LDS: no barrier
    // gather, unroll-4: 4 independent loads in flight
    int j = 0;
    for (; j + 4 <= cnt; j += 4) {
      int s0 = lsrc[wv][j], s1 = lsrc[wv][j+1], s2 = lsrc[wv][j+2], s3 = lsrc[wv][j+3];
      float q0 = lp[wv][j], q1 = lp[wv][j+1], q2 = lp[wv][j+2], q3 = lp[wv][j+3];
      float v0 = hsrc[(size_t)s0 * 64 + lane];
      float v1 = hsrc[(size_t)s1 * 64 + lane];
      float v2 = hsrc[(size_t)s2 * 64 + lane];
      float v3 = hsrc[(size_t)s3 * 64 + lane];
      acc += q0 * v0; acc += q1 * v1; acc += q2 * v2; acc += q3 * v3;
    }
    for (; j < cnt; ++j)
      acc += lp[wv][j] * hsrc[(size_t)lsrc[wv][j] * 64 + lane];
    M = Mn;
  }
  float v = acc / (S + 1e-16f) + bias[lane];
  v = fmaxf(v, 0.f);                              // agg2 (relu'd) value, k = lane
  srow[wv][lane] = v;                             // wave-local: no barrier
  float h3 = 0.f;
  #pragma unroll
  for (int kq = 0; kq < 16; ++kq) {               // h3 = srow @ W3
    float4 a4 = *(const float4*)&srow[wv][kq * 4];  // broadcast b128
    h3 += a4.x * sW3[(kq * 4 + 0) * 64 + lane];
    h3 += a4.y * sW3[(kq * 4 + 1) * 64 + lane];
    h3 += a4.z * sW3[(kq * 4 + 2) * 64 + lane];
    h3 += a4.w * sW3[(kq * 4 + 3) * 64 + lane];
  }
  float vs = wave_sum(h3 * a3s[lane]);
  float vd = wave_sum(h3 * a3d[lane]);
  if (lane == 0) { als3[n] = vs; ald3[n] = vd; }
  hout[(size_t)n * 64 + lane] = h3;               // raw h3
}

// ---------------- H=1 single-pass online-softmax aggregate + bias + relu
__global__ __launch_bounds__(256) void gat_aggregate(
    const float* __restrict__ hsrc, const float* __restrict__ als,
    const float* __restrict__ ald, const int* __restrict__ offs,
    const int* __restrict__ esrc, const float* __restrict__ bias,
    float* __restrict__ out) {
  int wv = threadIdx.x >> 6;
  int lane = threadIdx.x & 63;
  int n = blockIdx.x * 4 + wv;
  __shared__ float lp[4][64];
  __shared__ int   lsrc[4][64];
  int start = offs[n], end = offs[n + 1];
  float aldn = ald[n];
  float M = -INFINITY, S = 0.f, acc = 0.f;
  for (int j0 = start; j0 < end; j0 += 64) {
    int cnt = end - j0; if (cnt > 64) cnt = 64;
    int s = 0; float e = -INFINITY;
    if (lane < cnt) {
      s = esrc[j0 + lane];
      e = als[s] + aldn;
      e = (e > 0.f) ? e : 0.2f * e;               // leaky relu
    }
    float Mn = fmaxf(M, wave_max(e));             // self-loop => cnt>=1
    float scale = __expf(M - Mn);                 // first chunk: exp(-inf)=0
    float p = (lane < cnt) ? __expf(e - Mn) : 0.f;
    S = S * scale + wave_sum(p);
    acc *= scale;
    lp[wv][lane] = p;
    lsrc[wv][lane] = s;                           // wave-local LDS: no barrier
    // gather, unroll-4: 4 independent loads in flight
    int j = 0;
    for (; j + 4 <= cnt; j += 4) {
      int s0 = lsrc[wv][j], s1 = lsrc[wv][j+1], s2 = lsrc[wv][j+2], s3 = lsrc[wv][j+3];
      float q0 = lp[wv][j], q1 = lp[wv][j+1], q2 = lp[wv][j+2], q3 = lp[wv][j+3];
      float v0 = hsrc[(size_t)s0 * 64 + lane];
      float v1 = hsrc[(size_t)s1 * 64 + lane];
      float v2 = hsrc[(size_t)s2 * 64 + lane];
      float v3 = hsrc[(size_t)s3 * 64 + lane];
      acc += q0 * v0; acc += q1 * v1; acc += q2 * v2; acc += q3 * v3;
    }
    for (; j < cnt; ++j)
      acc += lp[wv][j] * hsrc[(size_t)lsrc[wv][j] * 64 + lane];
    M = Mn;
  }
  float v = acc / (S + 1e-16f) + bias[lane];
  out[(size_t)n * 64 + lane] = fmaxf(v, 0.f);
}

// ---------------- fc2 + fc3 + softmax, one wave per batch row ----------------
__global__ __launch_bounds__(256) void fc23_softmax(
    const float* __restrict__ h1, const float* __restrict__ W2,
    const float* __restrict__ b2, const float* __restrict__ W3,
    const float* __restrict__ b3, float* __restrict__ out) {
  int ws = threadIdx.x >> 6;
  int row = blockIdx.x * 4 + ws;
  int lane = threadIdx.x & 63;
  __shared__ float sh2[4][32];
  if (lane < 32) {
    float acc = b2[lane];
    for (int k = 0; k < 64; ++k) acc += h1[row * 64 + k] * W2[k * 32 + lane];
    sh2[ws][lane] = fmaxf(acc, 0.f);
  }
  __syncthreads();
  float logit = -INFINITY;
  if (lane < 16) {
    float acc = b3[lane];
    for (int k = 0; k < 32; ++k) acc += sh2[ws][k] * W3[k * 16 + lane];
    logit = acc;
  }
  float mx = logit;
  #pragma unroll
  for (int o = 8; o >= 1; o >>= 1) mx = fmaxf(mx, __shfl_xor(mx, o));
  float ex = (lane < 16) ? __expf(logit - mx) : 0.f;
  float ssum = ex;
  #pragma unroll
  for (int o = 8; o >= 1; o >>= 1) ssum += __shfl_xor(ssum, o);
  if (lane < 16) out[row * 16 + lane] = ex / ssum;
}

// ---------------- launcher ----------------
extern "C" void kernel_launch(void* const* d_in, const int* in_sizes, int n_in,
                              void* d_out, int out_size, void* d_ws, size_t ws_size,
                              hipStream_t stream) {
  const float* x0   = (const float*)d_in[0];
  const int*   ei   = (const int*)d_in[1];
  const float* W1   = (const float*)d_in[2];
  const float* a1s  = (const float*)d_in[3];
  const float* a1d  = (const float*)d_in[4];
  const float* b1   = (const float*)d_in[5];
  const float* W2   = (const float*)d_in[6];
  const float* a2s  = (const float*)d_in[7];
  const float* a2d  = (const float*)d_in[8];
  const float* b2   = (const float*)d_in[9];
  const float* W3   = (const float*)d_in[10];
  const float* a3s  = (const float*)d_in[11];
  const float* a3d  = (const float*)d_in[12];
  const float* b3   = (const float*)d_in[13];
  const float* fcW1 = (const float*)d_in[14];
  const float* fcb1 = (const float*)d_in[15];
  const float* fcW2 = (const float*)d_in[16];
  const float* fcb2 = (const float*)d_in[17];
  const float* fcW3 = (const float*)d_in[18];
  const float* fcb3 = (const float*)d_in[19];
  float* out = (float*)d_out;

  // workspace layout (~211 MB, matches round-2 footprint)
  float* agg1   = (float*)d_ws;                       // [N*256] 134 MB
  float* h23    = agg1 + (size_t)NN * 256;            // [N*64]  h2, later agg3
  float* agg23  = h23 + (size_t)NN * 64;              // [N*64]  h3
  float* als1   = agg23 + (size_t)NN * 64;            // [N*4]
  float* ald1   = als1 + (size_t)NN * 4;              // [N*4]
  float* als2   = ald1 + (size_t)NN * 4;              // [N]
  float* ald2   = als2 + NN;                          // [N]
  float* wts    = ald2 + NN;                          // [128]
  float* wtd    = wts + 128;                          // [128]
  int*   counts = (int*)(wtd + 128);                  // [N]
  int*   offs   = counts + NN;                        // [N+1]
  int*   cursor = offs + NN + 1;                      // [N]
  int*   esrc   = cursor + NN;                        // [ET]
  int*   blksums= esrc + ET;                          // [512]
  // overlays into agg1 (agg1 is dead after the GAT2 GEMM reads it)
  float* als3   = agg1;                               // [N]
  float* ald3   = agg1 + NN;                          // [N]
  float* hfc1   = agg1 + 2 * (size_t)NN;              // [B*64]

  // CSR build (reused by all 3 GAT layers)
  init_counts<<<NN / 256, 256, 0, stream>>>(counts);
  count_edges<<<EE / 256, 256, 0, stream>>>(ei, counts);
  scan_block<<<NN / 256, 256, 0, stream>>>(counts, offs, blksums);
  scan_sums<<<1, 512, 0, stream>>>(blksums);
  scan_add<<<NN / 256, 256, 0, stream>>>(offs, cursor, blksums);
  fill_csr<<<ET / 256, 256, 0, stream>>>(ei, cursor, esrc);

  // GAT1 in x-space: logits from tiny projections, aggregate x, then W1
  l1_avec<<<1, 128, 0, stream>>>(W1, a1s, a1d, wts, wtd);
  l1_logits<<<NN / 64, 256, 0, stream>>>(x0, wts, wtd, als1, ald1);
  gat1_fused<<<NN / 4, 256, 0, stream>>>(x0, als1, ald1, offs, esrc, W1, b1, agg1);
  // GAT2 GEMM: [N,256]@[256,64] -> h2 + als2/ald2
  gemm_n64<4, 32, true><<<NN / 32, 256, 0, stream>>>(agg1, W2, nullptr, a2s, a2d, h23, als2, ald2);
  // GAT2 aggregate fused with W3 GEMM -> h3 + als3/ald3
  gat_agg_w3<<<NN / 4, 256, 0, stream>>>(h23, als2, ald2, offs, esrc, b2,
                                         W3, a3s, a3d, agg23, als3, ald3);
  // GAT3 aggregate -> agg3 (into h23)
  gat_aggregate<<<NN / 4, 256, 0, stream>>>(agg23, als3, ald3, offs, esrc, b3, h23);
  // actor MLP
  gemm_n64<64, 16, false><<<BB / 16, 256, 0, stream>>>(h23, fcW1, fcb1, nullptr, nullptr, hfc1, nullptr, nullptr);
  fc23_softmax<<<BB / 4, 256, 0, stream>>>(hfc1, fcW2, fcb2, fcW3, fcb3, out);
}

// Round 9
// 673.453 us; speedup vs baseline: 1.1176x; 1.1176x over previous
//
#include <hip/hip_runtime.h>
#include <math.h>

#define NN 131072            // total nodes
#define FF 32                // input features
#define EE 524288            // random edges
#define ET (EE + NN)         // edges + self loops = 655360
#define BB 2048              // batch (graphs)

// ---------------- wave reductions (wave64) ----------------
__device__ __forceinline__ float wave_sum(float v) {
  #pragma unroll
  for (int o = 32; o >= 1; o >>= 1) v += __shfl_xor(v, o);
  return v;
}

// ---------------- CSR build (counting sort by dst) ----------------
__global__ void init_counts(int* counts) {
  int i = blockIdx.x * 256 + threadIdx.x;
  counts[i] = 1;                       // self loop contributes 1 per node
}

__global__ void count_edges(const int* __restrict__ ei, int* counts) {
  int e = blockIdx.x * 256 + threadIdx.x;
  atomicAdd(&counts[ei[EE + e]], 1);   // dst row of edge_index
}

__global__ void scan_block(const int* __restrict__ counts, int* offs, int* blksums) {
  __shared__ int sd[256];
  int t = threadIdx.x;
  int i = blockIdx.x * 256 + t;
  int v = counts[i];
  sd[t] = v;
  __syncthreads();
  for (int o = 1; o < 256; o <<= 1) {
    int x = (t >= o) ? sd[t - o] : 0;
    __syncthreads();
    sd[t] += x;
    __syncthreads();
  }
  offs[i] = sd[t] - v;                 // block-local exclusive scan
  if (t == 255) blksums[blockIdx.x] = sd[255];
}

__global__ void scan_sums(int* blksums) {  // 1 block x 512 threads
  __shared__ int sd[512];
  int t = threadIdx.x;
  int v = blksums[t];
  sd[t] = v;
  __syncthreads();
  for (int o = 1; o < 512; o <<= 1) {
    int x = (t >= o) ? sd[t - o] : 0;
    __syncthreads();
    sd[t] += x;
    __syncthreads();
  }
  blksums[t] = sd[t] - v;              // exclusive scan of block sums
}

__global__ void scan_add(int* offs, int* cursor, const int* __restrict__ blksums) {
  int i = blockIdx.x * 256 + threadIdx.x;
  int o = offs[i] + blksums[blockIdx.x];
  offs[i] = o;
  cursor[i] = o;
  if (i == 0) offs[NN] = ET;
}

__global__ void fill_csr(const int* __restrict__ ei, int* cursor,
                         int* esrc, int* edst) {
  int i = blockIdx.x * 256 + threadIdx.x;   // i < ET
  int s, d;
  if (i < EE) { s = ei[i]; d = ei[EE + i]; }
  else        { s = d = i - EE; }           // self loop
  int pos = atomicAdd(&cursor[d], 1);
  esrc[pos] = s;
  edst[pos] = d;
}

// ---------------- layer-1 attention vectors: wts[h,k] = sum_c W1[k,h*64+c]*a1s[h,c]
__global__ void l1_avec(const float* __restrict__ W1, const float* __restrict__ a1s,
                        const float* __restrict__ a1d, float* __restrict__ wts,
                        float* __restrict__ wtd) {
  int t = threadIdx.x;          // 128 threads: h = t>>5, k = t&31
  int h = t >> 5, k = t & 31;
  float as = 0.f, ad = 0.f;
  #pragma unroll
  for (int c = 0; c < 64; ++c) {
    float w = W1[k * 256 + h * 64 + c];
    as += w * a1s[h * 64 + c];
    ad += w * a1d[h * 64 + c];
  }
  wts[t] = as;
  wtd[t] = ad;
}

// ---------------- layer-1 logits: als[n,h] = x[n]·wts[h]  (64 nodes / block)
__global__ __launch_bounds__(256) void l1_logits(
    const float* __restrict__ x, const float* __restrict__ wts,
    const float* __restrict__ wtd, float* __restrict__ als, float* __restrict__ ald) {
  __shared__ float sx[64 * 33];     // padded stride 33: kill bank conflicts
  __shared__ float sts[128], std_[128];
  int t = threadIdx.x;
  int n0 = blockIdx.x * 64;
  #pragma unroll
  for (int j = 0; j < 8; ++j) {
    int idx = t + j * 256;          // 0..2047
    sx[(idx >> 5) * 33 + (idx & 31)] = x[(size_t)n0 * 32 + idx];
  }
  if (t < 128) sts[t] = wts[t]; else std_[t - 128] = wtd[t - 128];
  __syncthreads();
  int nl = t >> 2, h = t & 3;       // 64 nodes x 4 heads
  float vs = 0.f, vd = 0.f;
  #pragma unroll
  for (int k = 0; k < 32; ++k) {
    float xv = sx[nl * 33 + k];
    vs += xv * sts[h * 32 + k];
    vd += xv * std_[h * 32 + k];
  }
  als[(n0 + nl) * 4 + h] = vs;
  ald[(n0 + nl) * 4 + h] = vd;
}

// ---------------- per-edge softmax weights (no max-sub: logits are O(1))
// layer 1: 4 heads -> float4
__global__ void edge_w4(const int* __restrict__ esrc, const int* __restrict__ edst,
                        const float* __restrict__ als, const float* __restrict__ ald,
                        float4* __restrict__ w4) {
  int j = blockIdx.x * 256 + threadIdx.x;   // j < ET
  int s = esrc[j], d = edst[j];
  float4 a = ((const float4*)als)[s];
  float4 b = ((const float4*)ald)[d];
  float e0 = a.x + b.x; e0 = (e0 > 0.f) ? e0 : 0.2f * e0;
  float e1 = a.y + b.y; e1 = (e1 > 0.f) ? e1 : 0.2f * e1;
  float e2 = a.z + b.z; e2 = (e2 > 0.f) ? e2 : 0.2f * e2;
  float e3 = a.w + b.w; e3 = (e3 > 0.f) ? e3 : 0.2f * e3;
  w4[j] = make_float4(__expf(e0), __expf(e1), __expf(e2), __expf(e3));
}

// layers 2/3: 1 head
__global__ void edge_w1(const int* __restrict__ esrc, const int* __restrict__ edst,
                        const float* __restrict__ als, const float* __restrict__ ald,
                        float* __restrict__ w) {
  int j = blockIdx.x * 256 + threadIdx.x;   // j < ET
  float e = als[esrc[j]] + ald[edst[j]];
  e = (e > 0.f) ? e : 0.2f * e;
  w[j] = __expf(e);
}

// ---------------- fused GAT1 v3: wave per node, precomputed edge weights.
// lane = (k = lane&31, parity jp = lane>>5); parity groups take alternate edges.
// Per edge: w4 (16B broadcast) + x[src] row (128B/parity); xa_h += w_h*x, S_h += w_h.
// No wave reductions until the final shfl_xor(32) parity combine.
// Epilogue: agg1[n,h*64+c] = relu(xa[h]/S[h] · W1[:,h*64+c] + b1).
__global__ __launch_bounds__(256) void gat1_fused(
    const float* __restrict__ x, const int* __restrict__ offs,
    const int* __restrict__ esrc, const float4* __restrict__ w4arr,
    const float* __restrict__ W1, const float* __restrict__ b1,
    float* __restrict__ agg1) {
  __shared__ float sW1[32 * 256];   // 32 KB, whole W1
  __shared__ float sxa[4][128];     // [wave][h*32+k]
  int t = threadIdx.x;
  #pragma unroll
  for (int j = 0; j < 32; ++j) sW1[t + j * 256] = W1[t + j * 256];
  __syncthreads();
  int wv = t >> 6, lane = t & 63;
  int k = lane & 31, jp = lane >> 5;
  int n = blockIdx.x * 4 + wv;
  int start = offs[n], end = offs[n + 1];
  float xa0 = 0.f, xa1 = 0.f, xa2 = 0.f, xa3 = 0.f;
  float S0 = 0.f, S1 = 0.f, S2 = 0.f, S3 = 0.f;
  int j = start + jp;
  // unroll-2 over this parity's edges: 2 (esrc,w4,x) loads in flight
  for (; j + 2 < end; j += 4) {
    int sA_ = esrc[j], sB_ = esrc[j + 2];
    float4 wA = w4arr[j], wB = w4arr[j + 2];
    float xA = x[(size_t)sA_ * 32 + k];
    float xB = x[(size_t)sB_ * 32 + k];
    xa0 += wA.x * xA; xa1 += wA.y * xA; xa2 += wA.z * xA; xa3 += wA.w * xA;
    S0 += wA.x; S1 += wA.y; S2 += wA.z; S3 += wA.w;
    xa0 += wB.x * xB; xa1 += wB.y * xB; xa2 += wB.z * xB; xa3 += wB.w * xB;
    S0 += wB.x; S1 += wB.y; S2 += wB.z; S3 += wB.w;
  }
  if (j < end) {
    int s = esrc[j];
    float4 w = w4arr[j];
    float xv = x[(size_t)s * 32 + k];
    xa0 += w.x * xv; xa1 += w.y * xv; xa2 += w.z * xv; xa3 += w.w * xv;
    S0 += w.x; S1 += w.y; S2 += w.z; S3 += w.w;
  }
  // combine the two edge-parities
  xa0 += __shfl_xor(xa0, 32); S0 += __shfl_xor(S0, 32);
  xa1 += __shfl_xor(xa1, 32); S1 += __shfl_xor(S1, 32);
  xa2 += __shfl_xor(xa2, 32); S2 += __shfl_xor(S2, 32);
  xa3 += __shfl_xor(xa3, 32); S3 += __shfl_xor(S3, 32);
  sxa[wv][0 * 32 + k] = xa0 / (S0 + 1e-16f);
  sxa[wv][1 * 32 + k] = xa1 / (S1 + 1e-16f);
  sxa[wv][2 * 32 + k] = xa2 / (S2 + 1e-16f);
  sxa[wv][3 * 32 + k] = xa3 / (S3 + 1e-16f);   // wave-local: no barrier
  #pragma unroll
  for (int hh = 0; hh < 4; ++hh) {
    float acc = b1[hh * 64 + lane];
    #pragma unroll
    for (int kq = 0; kq < 8; ++kq) {
      float4 a4 = *(const float4*)&sxa[wv][hh * 32 + kq * 4];
      acc += a4.x * sW1[(kq * 4 + 0) * 256 + hh * 64 + lane];
      acc += a4.y * sW1[(kq * 4 + 1) * 256 + hh * 64 + lane];
      acc += a4.z * sW1[(kq * 4 + 2) * 256 + hh * 64 + lane];
      acc += a4.w * sW1[(kq * 4 + 3) * 256 + hh * 64 + lane];
    }
    agg1[(size_t)n * 256 + hh * 64 + lane] = fmaxf(acc, 0.f);
  }
}

// ---------------- float4 register-tiled GEMM: A[M,K] @ W[K,64]
template <int KTILES, int ROWS, bool AL>
__global__ __launch_bounds__(256) void gemm_n64(
    const float* __restrict__ A, const float* __restrict__ W,
    const float* __restrict__ bias, const float* __restrict__ a_s,
    const float* __restrict__ a_d, float* __restrict__ out,
    float* __restrict__ als, float* __restrict__ ald) {
  constexpr int K = KTILES * 64;
  constexpr int RPT = ROWS / 16;       // rows per thread
  constexpr int SAS = 68;              // sA stride: 16B-aligned, bank-staggered
  __shared__ float sW[64 * 64];        // [k][c] 16 KB
  __shared__ float sA[ROWS * SAS];
  int t = threadIdx.x;
  int cq = t & 15;
  int rs = t >> 4;
  int row0 = blockIdx.x * ROWS;
  float4 acc[RPT];
  #pragma unroll
  for (int rp = 0; rp < RPT; ++rp) acc[rp] = make_float4(0.f, 0.f, 0.f, 0.f);
  for (int kt = 0; kt < KTILES; ++kt) {
    #pragma unroll
    for (int j = 0; j < 4; ++j) {      // stage W tile [64][64]
      int li = t + j * 256;
      int kk = li >> 4, cc = (li & 15) * 4;
      *(float4*)&sW[kk * 64 + cc] =
          *(const float4*)&W[(size_t)(kt * 64 + kk) * 64 + cc];
    }
    #pragma unroll
    for (int j = 0; j < ROWS / 16; ++j) {  // stage A tile [ROWS][64]
      int li = t + j * 256;
      int r = li >> 4, kkq = (li & 15) * 4;
      *(float4*)&sA[r * SAS + kkq] =
          *(const float4*)&A[(size_t)(row0 + r) * K + kt * 64 + kkq];
    }
    __syncthreads();
    #pragma unroll
    for (int kq = 0; kq < 16; ++kq) {
      float4 a4[RPT];
      #pragma unroll
      for (int rp = 0; rp < RPT; ++rp)
        a4[rp] = *(const float4*)&sA[(rs * RPT + rp) * SAS + kq * 4];
      #pragma unroll
      for (int i = 0; i < 4; ++i) {
        float4 w4 = *(const float4*)&sW[(kq * 4 + i) * 64 + cq * 4];
        #pragma unroll
        for (int rp = 0; rp < RPT; ++rp) {
          float a = (i == 0) ? a4[rp].x : (i == 1) ? a4[rp].y
                  : (i == 2) ? a4[rp].z : a4[rp].w;
          acc[rp].x += a * w4.x; acc[rp].y += a * w4.y;
          acc[rp].z += a * w4.z; acc[rp].w += a * w4.w;
        }
      }
    }
    __syncthreads();
  }
  #pragma unroll
  for (int rp = 0; rp < RPT; ++rp) {
    int r = row0 + rs * RPT + rp;
    if constexpr (AL) {
      *(float4*)&out[(size_t)r * 64 + cq * 4] = acc[rp];   // raw h
      float4 s4 = *(const float4*)&a_s[cq * 4];
      float4 d4 = *(const float4*)&a_d[cq * 4];
      float vs = acc[rp].x * s4.x + acc[rp].y * s4.y + acc[rp].z * s4.z + acc[rp].w * s4.w;
      float vd = acc[rp].x * d4.x + acc[rp].y * d4.y + acc[rp].z * d4.z + acc[rp].w * d4.w;
      #pragma unroll
      for (int o = 8; o >= 1; o >>= 1) { vs += __shfl_xor(vs, o); vd += __shfl_xor(vd, o); }
      if (cq == 0) { als[r] = vs; ald[r] = vd; }
    } else {
      float4 b4 = *(const float4*)&bias[cq * 4];
      float4 v = acc[rp];
      v.x = fmaxf(v.x + b4.x, 0.f); v.y = fmaxf(v.y + b4.y, 0.f);
      v.z = fmaxf(v.z + b4.z, 0.f); v.w = fmaxf(v.w + b4.w, 0.f);
      *(float4*)&out[(size_t)r * 64 + cq * 4] = v;
    }
  }
}

// ---------------- layer-2 aggregate (precomputed w) fused with W3 GEMM + als3/ald3
__global__ __launch_bounds__(256) void gat_agg_w3(
    const float* __restrict__ hsrc, const float* __restrict__ warr,
    const int* __restrict__ offs, const int* __restrict__ esrc,
    const float* __restrict__ bias, const float* __restrict__ W3,
    const float* __restrict__ a3s, const float* __restrict__ a3d,
    float* __restrict__ hout, float* __restrict__ als3, float* __restrict__ ald3) {
  __shared__ float sW3[64 * 64];   // 16 KB
  __shared__ float srow[4][64];
  int t = threadIdx.x;
  #pragma unroll
  for (int j = 0; j < 4; ++j) {
    int li = t + j * 256;
    int kk = li >> 4, cc = (li & 15) * 4;
    *(float4*)&sW3[kk * 64 + cc] = *(const float4*)&W3[kk * 64 + cc];
  }
  __syncthreads();
  int wv = t >> 6, lane = t & 63;
  int n = blockIdx.x * 4 + wv;
  int start = offs[n], end = offs[n + 1];
  float acc = 0.f, S = 0.f;
  int j = start;
  for (; j + 4 <= end; j += 4) {          // 4 gathers in flight
    int s0 = esrc[j], s1 = esrc[j+1], s2 = esrc[j+2], s3 = esrc[j+3];
    float w0 = warr[j], w1 = warr[j+1], w2 = warr[j+2], w3 = warr[j+3];
    float v0 = hsrc[(size_t)s0 * 64 + lane];
    float v1 = hsrc[(size_t)s1 * 64 + lane];
    float v2 = hsrc[(size_t)s2 * 64 + lane];
    float v3 = hsrc[(size_t)s3 * 64 + lane];
    acc += w0 * v0; acc += w1 * v1; acc += w2 * v2; acc += w3 * v3;
    S += w0 + w1 + w2 + w3;
  }
  for (; j < end; ++j) {
    int s = esrc[j]; float w = warr[j];
    acc += w * hsrc[(size_t)s * 64 + lane];
    S += w;
  }
  float v = acc / (S + 1e-16f) + bias[lane];
  v = fmaxf(v, 0.f);                      // agg2 (relu'd) value, k = lane
  srow[wv][lane] = v;                     // wave-local: no barrier
  float h3 = 0.f;
  #pragma unroll
  for (int kq = 0; kq < 16; ++kq) {       // h3 = srow @ W3
    float4 a4 = *(const float4*)&srow[wv][kq * 4];  // broadcast b128
    h3 += a4.x * sW3[(kq * 4 + 0) * 64 + lane];
    h3 += a4.y * sW3[(kq * 4 + 1) * 64 + lane];
    h3 += a4.z * sW3[(kq * 4 + 2) * 64 + lane];
    h3 += a4.w * sW3[(kq * 4 + 3) * 64 + lane];
  }
  float vs = wave_sum(h3 * a3s[lane]);
  float vd = wave_sum(h3 * a3d[lane]);
  if (lane == 0) { als3[n] = vs; ald3[n] = vd; }
  hout[(size_t)n * 64 + lane] = h3;       // raw h3
}

// ---------------- H=1 aggregate with precomputed weights + bias + relu
__global__ __launch_bounds__(256) void gat_aggregate(
    const float* __restrict__ hsrc, const float* __restrict__ warr,
    const int* __restrict__ offs, const int* __restrict__ esrc,
    const float* __restrict__ bias, float* __restrict__ out) {
  int wv = threadIdx.x >> 6;
  int lane = threadIdx.x & 63;
  int n = blockIdx.x * 4 + wv;
  int start = offs[n], end = offs[n + 1];
  float acc = 0.f, S = 0.f;
  int j = start;
  for (; j + 4 <= end; j += 4) {          // 4 gathers in flight
    int s0 = esrc[j], s1 = esrc[j+1], s2 = esrc[j+2], s3 = esrc[j+3];
    float w0 = warr[j], w1 = warr[j+1], w2 = warr[j+2], w3 = warr[j+3];
    float v0 = hsrc[(size_t)s0 * 64 + lane];
    float v1 = hsrc[(size_t)s1 * 64 + lane];
    float v2 = hsrc[(size_t)s2 * 64 + lane];
    float v3 = hsrc[(size_t)s3 * 64 + lane];
    acc += w0 * v0; acc += w1 * v1; acc += w2 * v2; acc += w3 * v3;
    S += w0 + w1 + w2 + w3;
  }
  for (; j < end; ++j) {
    int s = esrc[j]; float w = warr[j];
    acc += w * hsrc[(size_t)s * 64 + lane];
    S += w;
  }
  float v = acc / (S + 1e-16f) + bias[lane];
  out[(size_t)n * 64 + lane] = fmaxf(v, 0.f);
}

// ---------------- fc2 + fc3 + softmax, one wave per batch row ----------------
__global__ __launch_bounds__(256) void fc23_softmax(
    const float* __restrict__ h1, const float* __restrict__ W2,
    const float* __restrict__ b2, const float* __restrict__ W3,
    const float* __restrict__ b3, float* __restrict__ out) {
  int ws = threadIdx.x >> 6;
  int row = blockIdx.x * 4 + ws;
  int lane = threadIdx.x & 63;
  __shared__ float sh2[4][32];
  if (lane < 32) {
    float acc = b2[lane];
    for (int k = 0; k < 64; ++k) acc += h1[row * 64 + k] * W2[k * 32 + lane];
    sh2[ws][lane] = fmaxf(acc, 0.f);
  }
  __syncthreads();
  float logit = -INFINITY;
  if (lane < 16) {
    float acc = b3[lane];
    for (int k = 0; k < 32; ++k) acc += sh2[ws][k] * W3[k * 16 + lane];
    logit = acc;
  }
  float mx = logit;
  #pragma unroll
  for (int o = 8; o >= 1; o >>= 1) mx = fmaxf(mx, __shfl_xor(mx, o));
  float ex = (lane < 16) ? __expf(logit - mx) : 0.f;
  float ssum = ex;
  #pragma unroll
  for (int o = 8; o >= 1; o >>= 1) ssum += __shfl_xor(ssum, o);
  if (lane < 16) out[row * 16 + lane] = ex / ssum;
}

// ---------------- launcher ----------------
extern "C" void kernel_launch(void* const* d_in, const int* in_sizes, int n_in,
                              void* d_out, int out_size, void* d_ws, size_t ws_size,
                              hipStream_t stream) {
  const float* x0   = (const float*)d_in[0];
  const int*   ei   = (const int*)d_in[1];
  const float* W1   = (const float*)d_in[2];
  const float* a1s  = (const float*)d_in[3];
  const float* a1d  = (const float*)d_in[4];
  const float* b1   = (const float*)d_in[5];
  const float* W2   = (const float*)d_in[6];
  const float* a2s  = (const float*)d_in[7];
  const float* a2d  = (const float*)d_in[8];
  const float* b2   = (const float*)d_in[9];
  const float* W3   = (const float*)d_in[10];
  const float* a3s  = (const float*)d_in[11];
  const float* a3d  = (const float*)d_in[12];
  const float* b3   = (const float*)d_in[13];
  const float* fcW1 = (const float*)d_in[14];
  const float* fcb1 = (const float*)d_in[15];
  const float* fcW2 = (const float*)d_in[16];
  const float* fcb2 = (const float*)d_in[17];
  const float* fcW3 = (const float*)d_in[18];
  const float* fcb3 = (const float*)d_in[19];
  float* out = (float*)d_out;

  // workspace layout (~214 MB)
  float* agg1   = (float*)d_ws;                       // [N*256] 134 MB
  float* h23    = agg1 + (size_t)NN * 256;            // [N*64]  h2, later agg3
  float* agg23  = h23 + (size_t)NN * 64;              // [N*64]  h3
  float* als1   = agg23 + (size_t)NN * 64;            // [N*4]
  float* ald1   = als1 + (size_t)NN * 4;              // [N*4]
  float* als2   = ald1 + (size_t)NN * 4;              // [N]
  float* ald2   = als2 + NN;                          // [N]
  float* wts    = ald2 + NN;                          // [128]
  float* wtd    = wts + 128;                          // [128]
  int*   counts = (int*)(wtd + 128);                  // [N]
  int*   offs   = counts + NN;                        // [N+1]
  int*   cursor = offs + NN + 1;                      // [N]
  int*   esrc   = cursor + NN;                        // [ET]
  int*   edst   = esrc + ET;                          // [ET]
  int*   blksums= edst + ET;                          // [512]
  // overlays:
  float4* w41   = (float4*)h23;                       // [ET] f4 (dead before h2 write)
  float* als3   = agg1;                               // [N]   (agg1 dead after gemm2)
  float* ald3   = agg1 + NN;                          // [N]
  float* hfc1   = agg1 + 2 * (size_t)NN;              // [B*64]
  float* w2     = agg1 + 4 * (size_t)NN;              // [ET]
  float* w3arr  = w2 + ET;                            // [ET]

  // CSR build (reused by all 3 GAT layers)
  init_counts<<<NN / 256, 256, 0, stream>>>(counts);
  count_edges<<<EE / 256, 256, 0, stream>>>(ei, counts);
  scan_block<<<NN / 256, 256, 0, stream>>>(counts, offs, blksums);
  scan_sums<<<1, 512, 0, stream>>>(blksums);
  scan_add<<<NN / 256, 256, 0, stream>>>(offs, cursor, blksums);
  fill_csr<<<ET / 256, 256, 0, stream>>>(ei, cursor, esrc, edst);

  // GAT1 in x-space: logits via tiny projections; per-edge weights; aggregate; W1
  l1_avec<<<1, 128, 0, stream>>>(W1, a1s, a1d, wts, wtd);
  l1_logits<<<NN / 64, 256, 0, stream>>>(x0, wts, wtd, als1, ald1);
  edge_w4<<<ET / 256, 256, 0, stream>>>(esrc, edst, als1, ald1, w41);
  gat1_fused<<<NN / 4, 256, 0, stream>>>(x0, offs, esrc, w41, W1, b1, agg1);
  // GAT2 GEMM: [N,256]@[256,64] -> h2 + als2/ald2
  gemm_n64<4, 32, true><<<NN / 32, 256, 0, stream>>>(agg1, W2, nullptr, a2s, a2d, h23, als2, ald2);
  edge_w1<<<ET / 256, 256, 0, stream>>>(esrc, edst, als2, ald2, w2);
  // GAT2 aggregate fused with W3 GEMM -> h3 + als3/ald3
  gat_agg_w3<<<NN / 4, 256, 0, stream>>>(h23, w2, offs, esrc, b2,
                                         W3, a3s, a3d, agg23, als3, ald3);
  edge_w1<<<ET / 256, 256, 0, stream>>>(esrc, edst, als3, ald3, w3arr);
  // GAT3 aggregate -> agg3 (into h23; h2 is dead)
  gat_aggregate<<<NN / 4, 256, 0, stream>>>(agg23, w3arr, offs, esrc, b3, h23);
  // actor MLP
  gemm_n64<64, 16, false><<<BB / 16, 256, 0, stream>>>(h23, fcW1, fcb1, nullptr, nullptr, hfc1, nullptr, nullptr);
  fc23_softmax<<<BB / 4, 256, 0, stream>>>(hfc1, fcW2, fcb2, fcW3, fcb3, out);
}

// Round 10
// 577.078 us; speedup vs baseline: 1.3043x; 1.1670x over previous
//
#include <hip/hip_runtime.h>
#include <math.h>

#define NN 131072            // total nodes
#define FF 32                // input features
#define EE 524288            // random edges
#define ET (EE + NN)         // edges + self loops = 655360
#define BB 2048              // batch (graphs)

// ---------------- CSR build (counting sort by dst) ----------------
__global__ void init_counts(int* counts) {
  int i = blockIdx.x * 256 + threadIdx.x;
  counts[i] = 1;                       // self loop contributes 1 per node
}

__global__ void count_edges(const int* __restrict__ ei, int* counts) {
  int e = blockIdx.x * 256 + threadIdx.x;
  atomicAdd(&counts[ei[EE + e]], 1);   // dst row of edge_index
}

__global__ void scan_block(const int* __restrict__ counts, int* offs, int* blksums) {
  __shared__ int sd[256];
  int t = threadIdx.x;
  int i = blockIdx.x * 256 + t;
  int v = counts[i];
  sd[t] = v;
  __syncthreads();
  for (int o = 1; o < 256; o <<= 1) {
    int x = (t >= o) ? sd[t - o] : 0;
    __syncthreads();
    sd[t] += x;
    __syncthreads();
  }
  offs[i] = sd[t] - v;                 // block-local exclusive scan
  if (t == 255) blksums[blockIdx.x] = sd[255];
}

__global__ void scan_sums(int* blksums) {  // 1 block x 512 threads
  __shared__ int sd[512];
  int t = threadIdx.x;
  int v = blksums[t];
  sd[t] = v;
  __syncthreads();
  for (int o = 1; o < 512; o <<= 1) {
    int x = (t >= o) ? sd[t - o] : 0;
    __syncthreads();
    sd[t] += x;
    __syncthreads();
  }
  blksums[t] = sd[t] - v;              // exclusive scan of block sums
}

__global__ void scan_add(int* offs, int* cursor, const int* __restrict__ blksums) {
  int i = blockIdx.x * 256 + threadIdx.x;
  int o = offs[i] + blksums[blockIdx.x];
  offs[i] = o;
  cursor[i] = o;
  if (i == 0) offs[NN] = ET;
}

__global__ void fill_csr(const int* __restrict__ ei, int* cursor,
                         int* esrc, int* edst) {
  int i = blockIdx.x * 256 + threadIdx.x;   // i < ET
  int s, d;
  if (i < EE) { s = ei[i]; d = ei[EE + i]; }
  else        { s = d = i - EE; }           // self loop
  int pos = atomicAdd(&cursor[d], 1);
  esrc[pos] = s;
  edst[pos] = d;
}

// ---------------- layer-1 attention vectors: wts[h,k] = sum_c W1[k,h*64+c]*a1s[h,c]
__global__ void l1_avec(const float* __restrict__ W1, const float* __restrict__ a1s,
                        const float* __restrict__ a1d, float* __restrict__ wts,
                        float* __restrict__ wtd) {
  int t = threadIdx.x;          // 128 threads: h = t>>5, k = t&31
  int h = t >> 5, k = t & 31;
  float as = 0.f, ad = 0.f;
  #pragma unroll
  for (int c = 0; c < 64; ++c) {
    float w = W1[k * 256 + h * 64 + c];
    as += w * a1s[h * 64 + c];
    ad += w * a1d[h * 64 + c];
  }
  wts[t] = as;
  wtd[t] = ad;
}

// ---------------- layer-1 logits: als[n,h] = x[n]·wts[h]  (64 nodes / block)
__global__ __launch_bounds__(256) void l1_logits(
    const float* __restrict__ x, const float* __restrict__ wts,
    const float* __restrict__ wtd, float* __restrict__ als, float* __restrict__ ald) {
  __shared__ float sx[64 * 33];     // padded stride 33: kill bank conflicts
  __shared__ float sts[128], std_[128];
  int t = threadIdx.x;
  int n0 = blockIdx.x * 64;
  #pragma unroll
  for (int j = 0; j < 8; ++j) {
    int idx = t + j * 256;          // 0..2047
    sx[(idx >> 5) * 33 + (idx & 31)] = x[(size_t)n0 * 32 + idx];
  }
  if (t < 128) sts[t] = wts[t]; else std_[t - 128] = wtd[t - 128];
  __syncthreads();
  int nl = t >> 2, h = t & 3;       // 64 nodes x 4 heads
  float vs = 0.f, vd = 0.f;
  #pragma unroll
  for (int k = 0; k < 32; ++k) {
    float xv = sx[nl * 33 + k];
    vs += xv * sts[h * 32 + k];
    vd += xv * std_[h * 32 + k];
  }
  als[(n0 + nl) * 4 + h] = vs;
  ald[(n0 + nl) * 4 + h] = vd;
}

// ---------------- per-edge softmax weights (no max-sub: logits are O(1))
// layer 1: 4 heads -> float4
__global__ void edge_w4(const int* __restrict__ esrc, const int* __restrict__ edst,
                        const float* __restrict__ als, const float* __restrict__ ald,
                        float4* __restrict__ w4) {
  int j = blockIdx.x * 256 + threadIdx.x;   // j < ET
  int s = esrc[j], d = edst[j];
  float4 a = ((const float4*)als)[s];
  float4 b = ((const float4*)ald)[d];
  float e0 = a.x + b.x; e0 = (e0 > 0.f) ? e0 : 0.2f * e0;
  float e1 = a.y + b.y; e1 = (e1 > 0.f) ? e1 : 0.2f * e1;
  float e2 = a.z + b.z; e2 = (e2 > 0.f) ? e2 : 0.2f * e2;
  float e3 = a.w + b.w; e3 = (e3 > 0.f) ? e3 : 0.2f * e3;
  w4[j] = make_float4(__expf(e0), __expf(e1), __expf(e2), __expf(e3));
}

// layers 2/3: 1 head
__global__ void edge_w1(const int* __restrict__ esrc, const int* __restrict__ edst,
                        const float* __restrict__ als, const float* __restrict__ ald,
                        float* __restrict__ w) {
  int j = blockIdx.x * 256 + threadIdx.x;   // j < ET
  float e = als[esrc[j]] + ald[edst[j]];
  e = (e > 0.f) ? e : 0.2f * e;
  w[j] = __expf(e);
}

// ---------------- GAT1 pure aggregate: wave per node, NO LDS, no epilogue.
// lane = (k = lane&31, parity jp = lane>>5); parities take alternate edges.
// Writes normalized x-space aggregate ya[n][h*32+k] (h=0..3).
__global__ __launch_bounds__(256) void gat1_agg(
    const float* __restrict__ x, const int* __restrict__ offs,
    const int* __restrict__ esrc, const float4* __restrict__ w4arr,
    float* __restrict__ ya) {
  int t = threadIdx.x;
  int wv = t >> 6, lane = t & 63;
  int k = lane & 31, jp = lane >> 5;
  int n = blockIdx.x * 4 + wv;
  int start = offs[n], end = offs[n + 1];
  float xa0 = 0.f, xa1 = 0.f, xa2 = 0.f, xa3 = 0.f;
  float S0 = 0.f, S1 = 0.f, S2 = 0.f, S3 = 0.f;
  int j = start + jp;
  // unroll-2 over this parity's edges: 2 (esrc,w4,x) loads in flight
  for (; j + 2 < end; j += 4) {
    int sA_ = esrc[j], sB_ = esrc[j + 2];
    float4 wA = w4arr[j], wB = w4arr[j + 2];
    float xA = x[(size_t)sA_ * 32 + k];
    float xB = x[(size_t)sB_ * 32 + k];
    xa0 += wA.x * xA; xa1 += wA.y * xA; xa2 += wA.z * xA; xa3 += wA.w * xA;
    S0 += wA.x; S1 += wA.y; S2 += wA.z; S3 += wA.w;
    xa0 += wB.x * xB; xa1 += wB.y * xB; xa2 += wB.z * xB; xa3 += wB.w * xB;
    S0 += wB.x; S1 += wB.y; S2 += wB.z; S3 += wB.w;
  }
  if (j < end) {
    int s = esrc[j];
    float4 w = w4arr[j];
    float xv = x[(size_t)s * 32 + k];
    xa0 += w.x * xv; xa1 += w.y * xv; xa2 += w.z * xv; xa3 += w.w * xv;
    S0 += w.x; S1 += w.y; S2 += w.z; S3 += w.w;
  }
  // combine the two edge-parities
  xa0 += __shfl_xor(xa0, 32); S0 += __shfl_xor(S0, 32);
  xa1 += __shfl_xor(xa1, 32); S1 += __shfl_xor(S1, 32);
  xa2 += __shfl_xor(xa2, 32); S2 += __shfl_xor(S2, 32);
  xa3 += __shfl_xor(xa3, 32); S3 += __shfl_xor(S3, 32);
  // parity 0 writes heads 0,1; parity 1 writes heads 2,3 (128B each)
  if (jp == 0) {
    ya[(size_t)n * 128 +  0 + k] = xa0 / (S0 + 1e-16f);
    ya[(size_t)n * 128 + 32 + k] = xa1 / (S1 + 1e-16f);
  } else {
    ya[(size_t)n * 128 + 64 + k] = xa2 / (S2 + 1e-16f);
    ya[(size_t)n * 128 + 96 + k] = xa3 / (S3 + 1e-16f);
  }
}

// ---------------- block-diagonal GEMM: agg1[n,h*64+c] = relu(ya[n,h*32:]·W1[:,h*64+c]+b1)
// 32 rows/block; thread = (row-slot rs = t>>6, col-quad cq = t&63, head hh = cq>>4).
__global__ __launch_bounds__(256) void gemm1_bd(
    const float* __restrict__ ya, const float* __restrict__ W1,
    const float* __restrict__ b1, float* __restrict__ agg1) {
  __shared__ float sW1[32 * 256];    // [k][c] 32 KB
  __shared__ float sA[32 * 144];     // [r][hh*36+kk], padded: bank-spread + 16B-aligned
  int t = threadIdx.x;
  int row0 = blockIdx.x * 32;
  #pragma unroll
  for (int j = 0; j < 8; ++j) {      // stage W1 (8192 floats)
    int li4 = t + j * 256;
    *(float4*)&sW1[li4 * 4] = *(const float4*)&W1[li4 * 4];
  }
  #pragma unroll
  for (int j = 0; j < 4; ++j) {      // stage ya tile (1024 float4)
    int li = t + j * 256;
    int r = li >> 5, f4 = li & 31;
    int hh = f4 >> 3, kk4 = (f4 & 7) * 4;
    *(float4*)&sA[r * 144 + hh * 36 + kk4] =
        *(const float4*)&ya[(size_t)(row0 + r) * 128 + f4 * 4];
  }
  __syncthreads();
  int cq = t & 63;                   // cols cq*4..+3
  int rs = t >> 6;                   // wave id
  int hh = cq >> 4;
  float4 acc[8];
  #pragma unroll
  for (int rp = 0; rp < 8; ++rp) acc[rp] = make_float4(0.f, 0.f, 0.f, 0.f);
  #pragma unroll
  for (int kk = 0; kk < 32; ++kk) {
    float4 w4 = *(const float4*)&sW1[kk * 256 + cq * 4];
    #pragma unroll
    for (int rp = 0; rp < 8; ++rp) {
      float a = sA[(rs * 8 + rp) * 144 + hh * 36 + kk];
      acc[rp].x += a * w4.x; acc[rp].y += a * w4.y;
      acc[rp].z += a * w4.z; acc[rp].w += a * w4.w;
    }
  }
  float4 b4 = *(const float4*)&b1[cq * 4];
  #pragma unroll
  for (int rp = 0; rp < 8; ++rp) {
    int r = row0 + rs * 8 + rp;
    float4 v = acc[rp];
    v.x = fmaxf(v.x + b4.x, 0.f); v.y = fmaxf(v.y + b4.y, 0.f);
    v.z = fmaxf(v.z + b4.z, 0.f); v.w = fmaxf(v.w + b4.w, 0.f);
    *(float4*)&agg1[(size_t)r * 256 + cq * 4] = v;
  }
}

// ---------------- float4 register-tiled GEMM: A[M,K] @ W[K,64]
template <int KTILES, int ROWS, bool AL>
__global__ __launch_bounds__(256) void gemm_n64(
    const float* __restrict__ A, const float* __restrict__ W,
    const float* __restrict__ bias, const float* __restrict__ a_s,
    const float* __restrict__ a_d, float* __restrict__ out,
    float* __restrict__ als, float* __restrict__ ald) {
  constexpr int K = KTILES * 64;
  constexpr int RPT = ROWS / 16;       // rows per thread
  constexpr int SAS = 68;              // sA stride: 16B-aligned, bank-staggered
  __shared__ float sW[64 * 64];        // [k][c] 16 KB
  __shared__ float sA[ROWS * SAS];
  int t = threadIdx.x;
  int cq = t & 15;
  int rs = t >> 4;
  int row0 = blockIdx.x * ROWS;
  float4 acc[RPT];
  #pragma unroll
  for (int rp = 0; rp < RPT; ++rp) acc[rp] = make_float4(0.f, 0.f, 0.f, 0.f);
  for (int kt = 0; kt < KTILES; ++kt) {
    #pragma unroll
    for (int j = 0; j < 4; ++j) {      // stage W tile [64][64]
      int li = t + j * 256;
      int kk = li >> 4, cc = (li & 15) * 4;
      *(float4*)&sW[kk * 64 + cc] =
          *(const float4*)&W[(size_t)(kt * 64 + kk) * 64 + cc];
    }
    #pragma unroll
    for (int j = 0; j < ROWS / 16; ++j) {  // stage A tile [ROWS][64]
      int li = t + j * 256;
      int r = li >> 4, kkq = (li & 15) * 4;
      *(float4*)&sA[r * SAS + kkq] =
          *(const float4*)&A[(size_t)(row0 + r) * K + kt * 64 + kkq];
    }
    __syncthreads();
    #pragma unroll
    for (int kq = 0; kq < 16; ++kq) {
      float4 a4[RPT];
      #pragma unroll
      for (int rp = 0; rp < RPT; ++rp)
        a4[rp] = *(const float4*)&sA[(rs * RPT + rp) * SAS + kq * 4];
      #pragma unroll
      for (int i = 0; i < 4; ++i) {
        float4 w4 = *(const float4*)&sW[(kq * 4 + i) * 64 + cq * 4];
        #pragma unroll
        for (int rp = 0; rp < RPT; ++rp) {
          float a = (i == 0) ? a4[rp].x : (i == 1) ? a4[rp].y
                  : (i == 2) ? a4[rp].z : a4[rp].w;
          acc[rp].x += a * w4.x; acc[rp].y += a * w4.y;
          acc[rp].z += a * w4.z; acc[rp].w += a * w4.w;
        }
      }
    }
    __syncthreads();
  }
  #pragma unroll
  for (int rp = 0; rp < RPT; ++rp) {
    int r = row0 + rs * RPT + rp;
    if constexpr (AL) {
      *(float4*)&out[(size_t)r * 64 + cq * 4] = acc[rp];   // raw h
      float4 s4 = *(const float4*)&a_s[cq * 4];
      float4 d4 = *(const float4*)&a_d[cq * 4];
      float vs = acc[rp].x * s4.x + acc[rp].y * s4.y + acc[rp].z * s4.z + acc[rp].w * s4.w;
      float vd = acc[rp].x * d4.x + acc[rp].y * d4.y + acc[rp].z * d4.z + acc[rp].w * d4.w;
      #pragma unroll
      for (int o = 8; o >= 1; o >>= 1) { vs += __shfl_xor(vs, o); vd += __shfl_xor(vd, o); }
      if (cq == 0) { als[r] = vs; ald[r] = vd; }
    } else {
      float4 b4 = *(const float4*)&bias[cq * 4];
      float4 v = acc[rp];
      v.x = fmaxf(v.x + b4.x, 0.f); v.y = fmaxf(v.y + b4.y, 0.f);
      v.z = fmaxf(v.z + b4.z, 0.f); v.w = fmaxf(v.w + b4.w, 0.f);
      *(float4*)&out[(size_t)r * 64 + cq * 4] = v;
    }
  }
}

// ---------------- H=1 aggregate with precomputed weights + bias + relu
__global__ __launch_bounds__(256) void gat_aggregate(
    const float* __restrict__ hsrc, const float* __restrict__ warr,
    const int* __restrict__ offs, const int* __restrict__ esrc,
    const float* __restrict__ bias, float* __restrict__ out) {
  int wv = threadIdx.x >> 6;
  int lane = threadIdx.x & 63;
  int n = blockIdx.x * 4 + wv;
  int start = offs[n], end = offs[n + 1];
  float acc = 0.f, S = 0.f;
  int j = start;
  for (; j + 4 <= end; j += 4) {          // 4 gathers in flight
    int s0 = esrc[j], s1 = esrc[j+1], s2 = esrc[j+2], s3 = esrc[j+3];
    float w0 = warr[j], w1 = warr[j+1], w2 = warr[j+2], w3 = warr[j+3];
    float v0 = hsrc[(size_t)s0 * 64 + lane];
    float v1 = hsrc[(size_t)s1 * 64 + lane];
    float v2 = hsrc[(size_t)s2 * 64 + lane];
    float v3 = hsrc[(size_t)s3 * 64 + lane];
    acc += w0 * v0; acc += w1 * v1; acc += w2 * v2; acc += w3 * v3;
    S += w0 + w1 + w2 + w3;
  }
  for (; j < end; ++j) {
    int s = esrc[j]; float w = warr[j];
    acc += w * hsrc[(size_t)s * 64 + lane];
    S += w;
  }
  float v = acc / (S + 1e-16f) + bias[lane];
  out[(size_t)n * 64 + lane] = fmaxf(v, 0.f);
}

// ---------------- fc2 + fc3 + softmax, one wave per batch row ----------------
__global__ __launch_bounds__(256) void fc23_softmax(
    const float* __restrict__ h1, const float* __restrict__ W2,
    const float* __restrict__ b2, const float* __restrict__ W3,
    const float* __restrict__ b3, float* __restrict__ out) {
  int ws = threadIdx.x >> 6;
  int row = blockIdx.x * 4 + ws;
  int lane = threadIdx.x & 63;
  __shared__ float sh2[4][32];
  if (lane < 32) {
    float acc = b2[lane];
    for (int k = 0; k < 64; ++k) acc += h1[row * 64 + k] * W2[k * 32 + lane];
    sh2[ws][lane] = fmaxf(acc, 0.f);
  }
  __syncthreads();
  float logit = -INFINITY;
  if (lane < 16) {
    float acc = b3[lane];
    for (int k = 0; k < 32; ++k) acc += sh2[ws][k] * W3[k * 16 + lane];
    logit = acc;
  }
  float mx = logit;
  #pragma unroll
  for (int o = 8; o >= 1; o >>= 1) mx = fmaxf(mx, __shfl_xor(mx, o));
  float ex = (lane < 16) ? __expf(logit - mx) : 0.f;
  float ssum = ex;
  #pragma unroll
  for (int o = 8; o >= 1; o >>= 1) ssum += __shfl_xor(ssum, o);
  if (lane < 16) out[row * 16 + lane] = ex / ssum;
}

// ---------------- launcher ----------------
extern "C" void kernel_launch(void* const* d_in, const int* in_sizes, int n_in,
                              void* d_out, int out_size, void* d_ws, size_t ws_size,
                              hipStream_t stream) {
  const float* x0   = (const float*)d_in[0];
  const int*   ei   = (const int*)d_in[1];
  const float* W1   = (const float*)d_in[2];
  const float* a1s  = (const float*)d_in[3];
  const float* a1d  = (const float*)d_in[4];
  const float* b1   = (const float*)d_in[5];
  const float* W2   = (const float*)d_in[6];
  const float* a2s  = (const float*)d_in[7];
  const float* a2d  = (const float*)d_in[8];
  const float* b2   = (const float*)d_in[9];
  const float* W3   = (const float*)d_in[10];
  const float* a3s  = (const float*)d_in[11];
  const float* a3d  = (const float*)d_in[12];
  const float* b3   = (const float*)d_in[13];
  const float* fcW1 = (const float*)d_in[14];
  const float* fcb1 = (const float*)d_in[15];
  const float* fcW2 = (const float*)d_in[16];
  const float* fcb2 = (const float*)d_in[17];
  const float* fcW3 = (const float*)d_in[18];
  const float* fcb3 = (const float*)d_in[19];
  float* out = (float*)d_out;

  // workspace layout (~214 MB)
  float* agg1   = (float*)d_ws;                       // [N*256] 134 MB
  float* h23    = agg1 + (size_t)NN * 256;            // [N*64]
  float* agg23  = h23 + (size_t)NN * 64;              // [N*64]
  float* als1   = agg23 + (size_t)NN * 64;            // [N*4]
  float* ald1   = als1 + (size_t)NN * 4;              // [N*4]
  float* als2   = ald1 + (size_t)NN * 4;              // [N]
  float* ald2   = als2 + NN;                          // [N]
  float* wts    = ald2 + NN;                          // [128]
  float* wtd    = wts + 128;                          // [128]
  int*   counts = (int*)(wtd + 128);                  // [N]
  int*   offs   = counts + NN;                        // [N+1]
  int*   cursor = offs + NN + 1;                      // [N]
  int*   esrc   = cursor + NN;                        // [ET]
  int*   edst   = esrc + ET;                          // [ET]
  int*   blksums= edst + ET;                          // [512]
  // overlays:
  float4* w41   = (float4*)agg1;                      // [ET] f4 (agg1 written later)
  float* ya     = h23;                                // [N*128] spans h23+agg23 (dead then)
  float* als3   = agg1;                               // [N]   (agg1 dead after gemm2)
  float* ald3   = agg1 + NN;                          // [N]
  float* hfc1   = agg1 + 2 * (size_t)NN;              // [B*64]
  float* w2     = agg1 + 4 * (size_t)NN;              // [ET]
  float* w3arr  = w2 + ET;                            // [ET]

  // CSR build (reused by all 3 GAT layers)
  init_counts<<<NN / 256, 256, 0, stream>>>(counts);
  count_edges<<<EE / 256, 256, 0, stream>>>(ei, counts);
  scan_block<<<NN / 256, 256, 0, stream>>>(counts, offs, blksums);
  scan_sums<<<1, 512, 0, stream>>>(blksums);
  scan_add<<<NN / 256, 256, 0, stream>>>(offs, cursor, blksums);
  fill_csr<<<ET / 256, 256, 0, stream>>>(ei, cursor, esrc, edst);

  // GAT1: logits via tiny projections; per-edge weights; pure aggregate; block-diag GEMM
  l1_avec<<<1, 128, 0, stream>>>(W1, a1s, a1d, wts, wtd);
  l1_logits<<<NN / 64, 256, 0, stream>>>(x0, wts, wtd, als1, ald1);
  edge_w4<<<ET / 256, 256, 0, stream>>>(esrc, edst, als1, ald1, w41);
  gat1_agg<<<NN / 4, 256, 0, stream>>>(x0, offs, esrc, w41, ya);
  gemm1_bd<<<NN / 32, 256, 0, stream>>>(ya, W1, b1, agg1);
  // GAT2 GEMM: [N,256]@[256,64] -> h2 + als2/ald2
  gemm_n64<4, 32, true><<<NN / 32, 256, 0, stream>>>(agg1, W2, nullptr, a2s, a2d, h23, als2, ald2);
  edge_w1<<<ET / 256, 256, 0, stream>>>(esrc, edst, als2, ald2, w2);
  // GAT2 aggregate -> agg2 (bias+relu)
  gat_aggregate<<<NN / 4, 256, 0, stream>>>(h23, w2, offs, esrc, b2, agg23);
  // GAT3 GEMM: [N,64]@[64,64] -> h3 + als3/ald3
  gemm_n64<1, 32, true><<<NN / 32, 256, 0, stream>>>(agg23, W3, nullptr, a3s, a3d, h23, als3, ald3);
  edge_w1<<<ET / 256, 256, 0, stream>>>(esrc, edst, als3, ald3, w3arr);
  // GAT3 aggregate -> agg3 (into agg23's slot after h3 read... h3 is in h23)
  gat_aggregate<<<NN / 4, 256, 0, stream>>>(h23, w3arr, offs, esrc, b3, agg23);
  // actor MLP
  gemm_n64<64, 16, false><<<BB / 16, 256, 0, stream>>>(agg23, fcW1, fcb1, nullptr, nullptr, hfc1, nullptr, nullptr);
  fc23_softmax<<<BB / 4, 256, 0, stream>>>(hfc1, fcW2, fcb2, fcW3, fcb3, out);
}

// Round 13
// 514.248 us; speedup vs baseline: 1.4636x; 1.1222x over previous
//
#include <hip/hip_runtime.h>
#include <math.h>

#define NN 131072            // total nodes
#define FF 32                // input features
#define EE 524288            // random edges
#define ET (EE + NN)         // edges + self loops = 655360
#define BB 2048              // batch (graphs)
#define KSPLIT 32            // fc1 K-split (4096 / 128)

// ---------------- CSR build (counting sort by dst) ----------------
__global__ void init_counts(int* counts) {
  int i = blockIdx.x * 256 + threadIdx.x;
  counts[i] = 1;                       // self loop contributes 1 per node
}

__global__ void count_edges(const int* __restrict__ ei, int* counts) {
  int e = blockIdx.x * 256 + threadIdx.x;
  atomicAdd(&counts[ei[EE + e]], 1);   // dst row of edge_index
}

__global__ void scan_block(const int* __restrict__ counts, int* offs, int* blksums) {
  __shared__ int sd[256];
  int t = threadIdx.x;
  int i = blockIdx.x * 256 + t;
  int v = counts[i];
  sd[t] = v;
  __syncthreads();
  for (int o = 1; o < 256; o <<= 1) {
    int x = (t >= o) ? sd[t - o] : 0;
    __syncthreads();
    sd[t] += x;
    __syncthreads();
  }
  offs[i] = sd[t] - v;                 // block-local exclusive scan
  if (t == 255) blksums[blockIdx.x] = sd[255];
}

__global__ void scan_sums(int* blksums) {  // 1 block x 512 threads
  __shared__ int sd[512];
  int t = threadIdx.x;
  int v = blksums[t];
  sd[t] = v;
  __syncthreads();
  for (int o = 1; o < 512; o <<= 1) {
    int x = (t >= o) ? sd[t - o] : 0;
    __syncthreads();
    sd[t] += x;
    __syncthreads();
  }
  blksums[t] = sd[t] - v;              // exclusive scan of block sums
}

__global__ void scan_add(int* offs, int* cursor, const int* __restrict__ blksums) {
  int i = blockIdx.x * 256 + threadIdx.x;
  int o = offs[i] + blksums[blockIdx.x];
  offs[i] = o;
  cursor[i] = o;
  if (i == 0) offs[NN] = ET;
}

__global__ void fill_csr(const int* __restrict__ ei, int* cursor,
                         int* esrc, int* edst) {
  int i = blockIdx.x * 256 + threadIdx.x;   // i < ET
  int s, d;
  if (i < EE) { s = ei[i]; d = ei[EE + i]; }
  else        { s = d = i - EE; }           // self loop
  int pos = atomicAdd(&cursor[d], 1);
  esrc[pos] = s;
  edst[pos] = d;
}

// ---------------- layer-1 attention vectors: wts[h,k] = sum_c W1[k,h*64+c]*a1s[h,c]
__global__ void l1_avec(const float* __restrict__ W1, const float* __restrict__ a1s,
                        const float* __restrict__ a1d, float* __restrict__ wts,
                        float* __restrict__ wtd) {
  int t = threadIdx.x;          // 128 threads: h = t>>5, k = t&31
  int h = t >> 5, k = t & 31;
  float as = 0.f, ad = 0.f;
  #pragma unroll
  for (int c = 0; c < 64; ++c) {
    float w = W1[k * 256 + h * 64 + c];
    as += w * a1s[h * 64 + c];
    ad += w * a1d[h * 64 + c];
  }
  wts[t] = as;
  wtd[t] = ad;
}

// ---------------- layer-1 logits: als[n,h] = x[n]·wts[h]  (64 nodes / block)
__global__ __launch_bounds__(256) void l1_logits(
    const float* __restrict__ x, const float* __restrict__ wts,
    const float* __restrict__ wtd, float* __restrict__ als, float* __restrict__ ald) {
  __shared__ float sx[64 * 33];     // padded stride 33: kill bank conflicts
  __shared__ float sts[128], std_[128];
  int t = threadIdx.x;
  int n0 = blockIdx.x * 64;
  #pragma unroll
  for (int j = 0; j < 8; ++j) {
    int idx = t + j * 256;          // 0..2047
    sx[(idx >> 5) * 33 + (idx & 31)] = x[(size_t)n0 * 32 + idx];
  }
  if (t < 128) sts[t] = wts[t]; else std_[t - 128] = wtd[t - 128];
  __syncthreads();
  int nl = t >> 2, h = t & 3;       // 64 nodes x 4 heads
  float vs = 0.f, vd = 0.f;
  #pragma unroll
  for (int k = 0; k < 32; ++k) {
    float xv = sx[nl * 33 + k];
    vs += xv * sts[h * 32 + k];
    vd += xv * std_[h * 32 + k];
  }
  als[(n0 + nl) * 4 + h] = vs;
  ald[(n0 + nl) * 4 + h] = vd;
}

// ---------------- per-edge softmax weights (no max-sub: logits are O(1))
// layer 1: 4 heads -> float4
__global__ void edge_w4(const int* __restrict__ esrc, const int* __restrict__ edst,
                        const float* __restrict__ als, const float* __restrict__ ald,
                        float4* __restrict__ w4) {
  int j = blockIdx.x * 256 + threadIdx.x;   // j < ET
  int s = esrc[j], d = edst[j];
  float4 a = ((const float4*)als)[s];
  float4 b = ((const float4*)ald)[d];
  float e0 = a.x + b.x; e0 = (e0 > 0.f) ? e0 : 0.2f * e0;
  float e1 = a.y + b.y; e1 = (e1 > 0.f) ? e1 : 0.2f * e1;
  float e2 = a.z + b.z; e2 = (e2 > 0.f) ? e2 : 0.2f * e2;
  float e3 = a.w + b.w; e3 = (e3 > 0.f) ? e3 : 0.2f * e3;
  w4[j] = make_float4(__expf(e0), __expf(e1), __expf(e2), __expf(e3));
}

// layers 2/3: 1 head
__global__ void edge_w1(const int* __restrict__ esrc, const int* __restrict__ edst,
                        const float* __restrict__ als, const float* __restrict__ ald,
                        float* __restrict__ w) {
  int j = blockIdx.x * 256 + threadIdx.x;   // j < ET
  float e = als[esrc[j]] + ald[edst[j]];
  e = (e > 0.f) ? e : 0.2f * e;
  w[j] = __expf(e);
}

// ---------------- GAT1 pure aggregate: wave per node, NO LDS, no epilogue.
__global__ __launch_bounds__(256) void gat1_agg(
    const float* __restrict__ x, const int* __restrict__ offs,
    const int* __restrict__ esrc, const float4* __restrict__ w4arr,
    float* __restrict__ ya) {
  int t = threadIdx.x;
  int wv = t >> 6, lane = t & 63;
  int k = lane & 31, jp = lane >> 5;
  int n = blockIdx.x * 4 + wv;
  int start = offs[n], end = offs[n + 1];
  float xa0 = 0.f, xa1 = 0.f, xa2 = 0.f, xa3 = 0.f;
  float S0 = 0.f, S1 = 0.f, S2 = 0.f, S3 = 0.f;
  int j = start + jp;
  // unroll-2 over this parity's edges: 2 (esrc,w4,x) loads in flight
  for (; j + 2 < end; j += 4) {
    int sA_ = esrc[j], sB_ = esrc[j + 2];
    float4 wA = w4arr[j], wB = w4arr[j + 2];
    float xA = x[(size_t)sA_ * 32 + k];
    float xB = x[(size_t)sB_ * 32 + k];
    xa0 += wA.x * xA; xa1 += wA.y * xA; xa2 += wA.z * xA; xa3 += wA.w * xA;
    S0 += wA.x; S1 += wA.y; S2 += wA.z; S3 += wA.w;
    xa0 += wB.x * xB; xa1 += wB.y * xB; xa2 += wB.z * xB; xa3 += wB.w * xB;
    S0 += wB.x; S1 += wB.y; S2 += wB.z; S3 += wB.w;
  }
  if (j < end) {
    int s = esrc[j];
    float4 w = w4arr[j];
    float xv = x[(size_t)s * 32 + k];
    xa0 += w.x * xv; xa1 += w.y * xv; xa2 += w.z * xv; xa3 += w.w * xv;
    S0 += w.x; S1 += w.y; S2 += w.z; S3 += w.w;
  }
  // combine the two edge-parities
  xa0 += __shfl_xor(xa0, 32); S0 += __shfl_xor(S0, 32);
  xa1 += __shfl_xor(xa1, 32); S1 += __shfl_xor(S1, 32);
  xa2 += __shfl_xor(xa2, 32); S2 += __shfl_xor(S2, 32);
  xa3 += __shfl_xor(xa3, 32); S3 += __shfl_xor(S3, 32);
  // parity 0 writes heads 0,1; parity 1 writes heads 2,3 (128B each)
  if (jp == 0) {
    ya[(size_t)n * 128 +  0 + k] = xa0 / (S0 + 1e-16f);
    ya[(size_t)n * 128 + 32 + k] = xa1 / (S1 + 1e-16f);
  } else {
    ya[(size_t)n * 128 + 64 + k] = xa2 / (S2 + 1e-16f);
    ya[(size_t)n * 128 + 96 + k] = xa3 / (S3 + 1e-16f);
  }
}

// ---------------- block-diagonal GEMM: agg1[n,h*64+c] = relu(ya[n,h*32:]·W1[:,h*64+c]+b1)
__global__ __launch_bounds__(256) void gemm1_bd(
    const float* __restrict__ ya, const float* __restrict__ W1,
    const float* __restrict__ b1, float* __restrict__ agg1) {
  __shared__ float sW1[32 * 256];    // [k][c] 32 KB
  __shared__ float sA[32 * 144];     // [r][hh*36+kk], padded: bank-spread + 16B-aligned
  int t = threadIdx.x;
  int row0 = blockIdx.x * 32;
  #pragma unroll
  for (int j = 0; j < 8; ++j) {      // stage W1 (8192 floats)
    int li4 = t + j * 256;
    *(float4*)&sW1[li4 * 4] = *(const float4*)&W1[li4 * 4];
  }
  #pragma unroll
  for (int j = 0; j < 4; ++j) {      // stage ya tile (1024 float4)
    int li = t + j * 256;
    int r = li >> 5, f4 = li & 31;
    int hh = f4 >> 3, kk4 = (f4 & 7) * 4;
    *(float4*)&sA[r * 144 + hh * 36 + kk4] =
        *(const float4*)&ya[(size_t)(row0 + r) * 128 + f4 * 4];
  }
  __syncthreads();
  int cq = t & 63;                   // cols cq*4..+3
  int rs = t >> 6;                   // wave id
  int hh = cq >> 4;
  float4 acc[8];
  #pragma unroll
  for (int rp = 0; rp < 8; ++rp) acc[rp] = make_float4(0.f, 0.f, 0.f, 0.f);
  #pragma unroll
  for (int kk = 0; kk < 32; ++kk) {
    float4 w4 = *(const float4*)&sW1[kk * 256 + cq * 4];
    #pragma unroll
    for (int rp = 0; rp < 8; ++rp) {
      float a = sA[(rs * 8 + rp) * 144 + hh * 36 + kk];
      acc[rp].x += a * w4.x; acc[rp].y += a * w4.y;
      acc[rp].z += a * w4.z; acc[rp].w += a * w4.w;
    }
  }
  float4 b4 = *(const float4*)&b1[cq * 4];
  #pragma unroll
  for (int rp = 0; rp < 8; ++rp) {
    int r = row0 + rs * 8 + rp;
    float4 v = acc[rp];
    v.x = fmaxf(v.x + b4.x, 0.f); v.y = fmaxf(v.y + b4.y, 0.f);
    v.z = fmaxf(v.z + b4.z, 0.f); v.w = fmaxf(v.w + b4.w, 0.f);
    *(float4*)&agg1[(size_t)r * 256 + cq * 4] = v;
  }
}

// ---------------- float4 register-tiled GEMM: A[M,K] @ W[K,64]
template <int KTILES, int ROWS, bool AL>
__global__ __launch_bounds__(256) void gemm_n64(
    const float* __restrict__ A, const float* __restrict__ W,
    const float* __restrict__ bias, const float* __restrict__ a_s,
    const float* __restrict__ a_d, float* __restrict__ out,
    float* __restrict__ als, float* __restrict__ ald) {
  constexpr int K = KTILES * 64;
  constexpr int RPT = ROWS / 16;       // rows per thread
  constexpr int SAS = 68;              // sA stride: 16B-aligned, bank-staggered
  __shared__ float sW[64 * 64];        // [k][c] 16 KB
  __shared__ float sA[ROWS * SAS];
  int t = threadIdx.x;
  int cq = t & 15;
  int rs = t >> 4;
  int row0 = blockIdx.x * ROWS;
  float4 acc[RPT];
  #pragma unroll
  for (int rp = 0; rp < RPT; ++rp) acc[rp] = make_float4(0.f, 0.f, 0.f, 0.f);
  for (int kt = 0; kt < KTILES; ++kt) {
    #pragma unroll
    for (int j = 0; j < 4; ++j) {      // stage W tile [64][64]
      int li = t + j * 256;
      int kk = li >> 4, cc = (li & 15) * 4;
      *(float4*)&sW[kk * 64 + cc] =
          *(const float4*)&W[(size_t)(kt * 64 + kk) * 64 + cc];
    }
    #pragma unroll
    for (int j = 0; j < ROWS / 16; ++j) {  // stage A tile [ROWS][64]
      int li = t + j * 256;
      int r = li >> 4, kkq = (li & 15) * 4;
      *(float4*)&sA[r * SAS + kkq] =
          *(const float4*)&A[(size_t)(row0 + r) * K + kt * 64 + kkq];
    }
    __syncthreads();
    #pragma unroll
    for (int kq = 0; kq < 16; ++kq) {
      float4 a4[RPT];
      #pragma unroll
      for (int rp = 0; rp < RPT; ++rp)
        a4[rp] = *(const float4*)&sA[(rs * RPT + rp) * SAS + kq * 4];
      #pragma unroll
      for (int i = 0; i < 4; ++i) {
        float4 w4 = *(const float4*)&sW[(kq * 4 + i) * 64 + cq * 4];
        #pragma unroll
        for (int rp = 0; rp < RPT; ++rp) {
          float a = (i == 0) ? a4[rp].x : (i == 1) ? a4[rp].y
                  : (i == 2) ? a4[rp].z : a4[rp].w;
          acc[rp].x += a * w4.x; acc[rp].y += a * w4.y;
          acc[rp].z += a * w4.z; acc[rp].w += a * w4.w;
        }
      }
    }
    __syncthreads();
  }
  #pragma unroll
  for (int rp = 0; rp < RPT; ++rp) {
    int r = row0 + rs * RPT + rp;
    if constexpr (AL) {
      *(float4*)&out[(size_t)r * 64 + cq * 4] = acc[rp];   // raw h
      float4 s4 = *(const float4*)&a_s[cq * 4];
      float4 d4 = *(const float4*)&a_d[cq * 4];
      float vs = acc[rp].x * s4.x + acc[rp].y * s4.y + acc[rp].z * s4.z + acc[rp].w * s4.w;
      float vd = acc[rp].x * d4.x + acc[rp].y * d4.y + acc[rp].z * d4.z + acc[rp].w * d4.w;
      #pragma unroll
      for (int o = 8; o >= 1; o >>= 1) { vs += __shfl_xor(vs, o); vd += __shfl_xor(vd, o); }
      if (cq == 0) { als[r] = vs; ald[r] = vd; }
    } else {
      float4 b4 = *(const float4*)&bias[cq * 4];
      float4 v = acc[rp];
      v.x = fmaxf(v.x + b4.x, 0.f); v.y = fmaxf(v.y + b4.y, 0.f);
      v.z = fmaxf(v.z + b4.z, 0.f); v.w = fmaxf(v.w + b4.w, 0.f);
      *(float4*)&out[(size_t)r * 64 + cq * 4] = v;
    }
  }
}

// ---------------- fc1 split-K: part[sp][row][c] = A[row, sp*128:+128]·W[sp*128:+128, c]
// block = (row-tile of 16) x (ksplit of 128); grid = 128*32 = 4096 blocks.
__global__ __launch_bounds__(256) void gemm_fc1_split(
    const float* __restrict__ A, const float* __restrict__ W,
    float* __restrict__ part) {
  __shared__ float sW[128 * 64];     // 32 KB
  __shared__ float sA[16 * 132];     // 16 rows x 128 k, padded stride
  int t = threadIdx.x;
  int bid = blockIdx.x;
  int rt = bid >> 5;                 // row tile (0..127)
  int sp = bid & 31;                 // k-split  (0..31)
  #pragma unroll
  for (int j = 0; j < 8; ++j) {      // stage W chunk [128][64]
    int li = t + j * 256;
    int kk = li >> 4, cc = (li & 15) * 4;
    *(float4*)&sW[kk * 64 + cc] =
        *(const float4*)&W[(size_t)(sp * 128 + kk) * 64 + cc];
  }
  #pragma unroll
  for (int j = 0; j < 2; ++j) {      // stage A tile [16][128]
    int li = t + j * 256;
    int r = li >> 5, kq4 = (li & 31) * 4;
    *(float4*)&sA[r * 132 + kq4] =
        *(const float4*)&A[(size_t)(rt * 16 + r) * 4096 + sp * 128 + kq4];
  }
  __syncthreads();
  int cq = t & 15;                   // col quad
  int rs = t >> 4;                   // row slot (0..15)
  float4 acc = make_float4(0.f, 0.f, 0.f, 0.f);
  #pragma unroll
  for (int kq = 0; kq < 32; ++kq) {
    float4 a4 = *(const float4*)&sA[rs * 132 + kq * 4];
    #pragma unroll
    for (int i = 0; i < 4; ++i) {
      float4 w4 = *(const float4*)&sW[(kq * 4 + i) * 64 + cq * 4];
      float a = (i == 0) ? a4.x : (i == 1) ? a4.y : (i == 2) ? a4.z : a4.w;
      acc.x += a * w4.x; acc.y += a * w4.y; acc.z += a * w4.z; acc.w += a * w4.w;
    }
  }
  *(float4*)&part[((size_t)sp * BB + rt * 16 + rs) * 64 + cq * 4] = acc;
}

// ---------------- H=1 aggregate with precomputed weights + bias + relu
__global__ __launch_bounds__(256) void gat_aggregate(
    const float* __restrict__ hsrc, const float* __restrict__ warr,
    const int* __restrict__ offs, const int* __restrict__ esrc,
    const float* __restrict__ bias, float* __restrict__ out) {
  int wv = threadIdx.x >> 6;
  int lane = threadIdx.x & 63;
  int n = blockIdx.x * 4 + wv;
  int start = offs[n], end = offs[n + 1];
  float acc = 0.f, S = 0.f;
  int j = start;
  for (; j + 4 <= end; j += 4) {          // 4 gathers in flight
    int s0 = esrc[j], s1 = esrc[j+1], s2 = esrc[j+2], s3 = esrc[j+3];
    float w0 = warr[j], w1 = warr[j+1], w2 = warr[j+2], w3 = warr[j+3];
    float v0 = hsrc[(size_t)s0 * 64 + lane];
    float v1 = hsrc[(size_t)s1 * 64 + lane];
    float v2 = hsrc[(size_t)s2 * 64 + lane];
    float v3 = hsrc[(size_t)s3 * 64 + lane];
    acc += w0 * v0; acc += w1 * v1; acc += w2 * v2; acc += w3 * v3;
    S += w0 + w1 + w2 + w3;
  }
  for (; j < end; ++j) {
    int s = esrc[j]; float w = warr[j];
    acc += w * hsrc[(size_t)s * 64 + lane];
    S += w;
  }
  float v = acc / (S + 1e-16f) + bias[lane];
  out[(size_t)n * 64 + lane] = fmaxf(v, 0.f);
}

// ---------------- fused fc1-reduce + fc2 + fc3 + softmax, one wave per batch row
__global__ __launch_bounds__(256) void fc23_softmax(
    const float* __restrict__ part, const float* __restrict__ fcb1,
    const float* __restrict__ W2, const float* __restrict__ b2,
    const float* __restrict__ W3, const float* __restrict__ b3,
    float* __restrict__ out) {
  int ws = threadIdx.x >> 6;
  int row = blockIdx.x * 4 + ws;
  int lane = threadIdx.x & 63;
  __shared__ float sh1[4][64];
  __shared__ float sh2[4][32];
  // reduce the 32 k-split partials for h1[row][lane] (coalesced 256B per sp)
  float h1 = fcb1[lane];
  #pragma unroll
  for (int sp = 0; sp < KSPLIT; sp += 4) {
    float p0 = part[((size_t)(sp + 0) * BB + row) * 64 + lane];
    float p1 = part[((size_t)(sp + 1) * BB + row) * 64 + lane];
    float p2 = part[((size_t)(sp + 2) * BB + row) * 64 + lane];
    float p3 = part[((size_t)(sp + 3) * BB + row) * 64 + lane];
    h1 += p0 + p1 + p2 + p3;
  }
  sh1[ws][lane] = fmaxf(h1, 0.f);     // wave-local: no barrier
  if (lane < 32) {
    float acc = b2[lane];
    #pragma unroll
    for (int k = 0; k < 64; ++k) acc += sh1[ws][k] * W2[k * 32 + lane];
    sh2[ws][lane] = fmaxf(acc, 0.f);  // wave-local
  }
  float logit = -INFINITY;
  if (lane < 16) {
    float acc = b3[lane];
    #pragma unroll
    for (int k = 0; k < 32; ++k) acc += sh2[ws][k] * W3[k * 16 + lane];
    logit = acc;
  }
  float mx = logit;
  #pragma unroll
  for (int o = 8; o >= 1; o >>= 1) mx = fmaxf(mx, __shfl_xor(mx, o));
  float ex = (lane < 16) ? __expf(logit - mx) : 0.f;
  float ssum = ex;
  #pragma unroll
  for (int o = 8; o >= 1; o >>= 1) ssum += __shfl_xor(ssum, o);
  if (lane < 16) out[row * 16 + lane] = ex / ssum;
}

// ---------------- launcher ----------------
extern "C" void kernel_launch(void* const* d_in, const int* in_sizes, int n_in,
                              void* d_out, int out_size, void* d_ws, size_t ws_size,
                              hipStream_t stream) {
  const float* x0   = (const float*)d_in[0];
  const int*   ei   = (const int*)d_in[1];
  const float* W1   = (const float*)d_in[2];
  const float* a1s  = (const float*)d_in[3];
  const float* a1d  = (const float*)d_in[4];
  const float* b1   = (const float*)d_in[5];
  const float* W2   = (const float*)d_in[6];
  const float* a2s  = (const float*)d_in[7];
  const float* a2d  = (const float*)d_in[8];
  const float* b2   = (const float*)d_in[9];
  const float* W3   = (const float*)d_in[10];
  const float* a3s  = (const float*)d_in[11];
  const float* a3d  = (const float*)d_in[12];
  const float* b3   = (const float*)d_in[13];
  const float* fcW1 = (const float*)d_in[14];
  const float* fcb1 = (const float*)d_in[15];
  const float* fcW2 = (const float*)d_in[16];
  const float* fcb2 = (const float*)d_in[17];
  const float* fcW3 = (const float*)d_in[18];
  const float* fcb3 = (const float*)d_in[19];
  float* out = (float*)d_out;

  // workspace layout (~214 MB)
  float* agg1   = (float*)d_ws;                       // [N*256] 134 MB
  float* h23    = agg1 + (size_t)NN * 256;            // [N*64]
  float* agg23  = h23 + (size_t)NN * 64;              // [N*64]
  float* als1   = agg23 + (size_t)NN * 64;            // [N*4]
  float* ald1   = als1 + (size_t)NN * 4;              // [N*4]
  float* als2   = ald1 + (size_t)NN * 4;              // [N]
  float* ald2   = als2 + NN;                          // [N]
  float* wts    = ald2 + NN;                          // [128]
  float* wtd    = wts + 128;                          // [128]
  int*   counts = (int*)(wtd + 128);                  // [N]
  int*   offs   = counts + NN;                        // [N+1]
  int*   cursor = offs + NN + 1;                      // [N]
  int*   esrc   = cursor + NN;                        // [ET]
  int*   edst   = esrc + ET;                          // [ET]
  int*   blksums= edst + ET;                          // [512]
  // overlays (into agg1, which is dead after the GAT2 GEMM reads it):
  float4* w41   = (float4*)agg1;                      // [ET] f4 (pre-agg1-write)
  float* ya     = h23;                                // [N*128] spans h23+agg23
  float* als3   = agg1;                               // [N]
  float* ald3   = agg1 + NN;                          // [N]
  float* w2     = agg1 + 2 * (size_t)NN;              // [ET]
  float* w3arr  = w2 + ET;                            // [ET]
  float* part   = w3arr + ET;                         // [KSPLIT*B*64] 16.8 MB

  // CSR build (reused by all 3 GAT layers)
  init_counts<<<NN / 256, 256, 0, stream>>>(counts);
  count_edges<<<EE / 256, 256, 0, stream>>>(ei, counts);
  scan_block<<<NN / 256, 256, 0, stream>>>(counts, offs, blksums);
  scan_sums<<<1, 512, 0, stream>>>(blksums);
  scan_add<<<NN / 256, 256, 0, stream>>>(offs, cursor, blksums);
  fill_csr<<<ET / 256, 256, 0, stream>>>(ei, cursor, esrc, edst);

  // GAT1: logits via tiny projections; per-edge weights; pure aggregate; block-diag GEMM
  l1_avec<<<1, 128, 0, stream>>>(W1, a1s, a1d, wts, wtd);
  l1_logits<<<NN / 64, 256, 0, stream>>>(x0, wts, wtd, als1, ald1);
  edge_w4<<<ET / 256, 256, 0, stream>>>(esrc, edst, als1, ald1, w41);
  gat1_agg<<<NN / 4, 256, 0, stream>>>(x0, offs, esrc, w41, ya);
  gemm1_bd<<<NN / 32, 256, 0, stream>>>(ya, W1, b1, agg1);
  // GAT2 GEMM: [N,256]@[256,64] -> h2 + als2/ald2
  gemm_n64<4, 32, true><<<NN / 32, 256, 0, stream>>>(agg1, W2, nullptr, a2s, a2d, h23, als2, ald2);
  edge_w1<<<ET / 256, 256, 0, stream>>>(esrc, edst, als2, ald2, w2);
  // GAT2 aggregate -> agg2 (bias+relu)
  gat_aggregate<<<NN / 4, 256, 0, stream>>>(h23, w2, offs, esrc, b2, agg23);
  // GAT3 GEMM: [N,64]@[64,64] -> h3 + als3/ald3
  gemm_n64<1, 32, true><<<NN / 32, 256, 0, stream>>>(agg23, W3, nullptr, a3s, a3d, h23, als3, ald3);
  edge_w1<<<ET / 256, 256, 0, stream>>>(esrc, edst, als3, ald3, w3arr);
  // GAT3 aggregate -> agg3
  gat_aggregate<<<NN / 4, 256, 0, stream>>>(h23, w3arr, offs, esrc, b3, agg23);
  // actor MLP: split-K fc1 partials, then fused reduce+fc2+fc3+softmax
  gemm_fc1_split<<<128 * KSPLIT, 256, 0, stream>>>(agg23, fcW1, part);
  fc23_softmax<<<BB / 4, 256, 0, stream>>>(part, fcb1, fcW2, fcb2, fcW3, fcb3, out);
}

// Round 14
// 498.821 us; speedup vs baseline: 1.5089x; 1.0309x over previous
//
#include <hip/hip_runtime.h>
#include <math.h>

#define NN 131072            // total nodes
#define FF 32                // input features
#define EE 524288            // random edges
#define ET (EE + NN)         // edges + self loops = 655360
#define BB 2048              // batch (graphs)
#define KSPLIT 32            // fc1 K-split (4096 / 128)

// ---------------- CSR build (counting sort by dst) ----------------
__global__ void init_counts(int* counts) {
  int i = blockIdx.x * 256 + threadIdx.x;
  counts[i] = 1;                       // self loop contributes 1 per node
}

__global__ void count_edges(const int* __restrict__ ei, int* counts) {
  int e = blockIdx.x * 256 + threadIdx.x;
  atomicAdd(&counts[ei[EE + e]], 1);   // dst row of edge_index
}

__global__ void scan_block(const int* __restrict__ counts, int* offs, int* blksums) {
  __shared__ int sd[256];
  int t = threadIdx.x;
  int i = blockIdx.x * 256 + t;
  int v = counts[i];
  sd[t] = v;
  __syncthreads();
  for (int o = 1; o < 256; o <<= 1) {
    int x = (t >= o) ? sd[t - o] : 0;
    __syncthreads();
    sd[t] += x;
    __syncthreads();
  }
  offs[i] = sd[t] - v;                 // block-local exclusive scan
  if (t == 255) blksums[blockIdx.x] = sd[255];
}

__global__ void scan_sums(int* blksums) {  // 1 block x 512 threads
  __shared__ int sd[512];
  int t = threadIdx.x;
  int v = blksums[t];
  sd[t] = v;
  __syncthreads();
  for (int o = 1; o < 512; o <<= 1) {
    int x = (t >= o) ? sd[t - o] : 0;
    __syncthreads();
    sd[t] += x;
    __syncthreads();
  }
  blksums[t] = sd[t] - v;              // exclusive scan of block sums
}

__global__ void scan_add(int* offs, int* cursor, const int* __restrict__ blksums) {
  int i = blockIdx.x * 256 + threadIdx.x;
  int o = offs[i] + blksums[blockIdx.x];
  offs[i] = o;
  cursor[i] = o;
  if (i == 0) offs[NN] = ET;
}

__global__ void fill_csr(const int* __restrict__ ei, int* cursor,
                         int* esrc, int* edst) {
  int i = blockIdx.x * 256 + threadIdx.x;   // i < ET
  int s, d;
  if (i < EE) { s = ei[i]; d = ei[EE + i]; }
  else        { s = d = i - EE; }           // self loop
  int pos = atomicAdd(&cursor[d], 1);
  esrc[pos] = s;
  edst[pos] = d;
}

// ---------------- layer-1 attention vectors: wts[h,k] = sum_c W1[k,h*64+c]*a1s[h,c]
__global__ void l1_avec(const float* __restrict__ W1, const float* __restrict__ a1s,
                        const float* __restrict__ a1d, float* __restrict__ wts,
                        float* __restrict__ wtd) {
  int t = threadIdx.x;          // 128 threads: h = t>>5, k = t&31
  int h = t >> 5, k = t & 31;
  float as = 0.f, ad = 0.f;
  #pragma unroll
  for (int c = 0; c < 64; ++c) {
    float w = W1[k * 256 + h * 64 + c];
    as += w * a1s[h * 64 + c];
    ad += w * a1d[h * 64 + c];
  }
  wts[t] = as;
  wtd[t] = ad;
}

// ---------------- layer-1 logits: als[n,h] = x[n]·wts[h]  (64 nodes / block)
__global__ __launch_bounds__(256) void l1_logits(
    const float* __restrict__ x, const float* __restrict__ wts,
    const float* __restrict__ wtd, float* __restrict__ als, float* __restrict__ ald) {
  __shared__ float sx[64 * 33];     // padded stride 33: kill bank conflicts
  __shared__ float sts[128], std_[128];
  int t = threadIdx.x;
  int n0 = blockIdx.x * 64;
  #pragma unroll
  for (int j = 0; j < 8; ++j) {
    int idx = t + j * 256;          // 0..2047
    sx[(idx >> 5) * 33 + (idx & 31)] = x[(size_t)n0 * 32 + idx];
  }
  if (t < 128) sts[t] = wts[t]; else std_[t - 128] = wtd[t - 128];
  __syncthreads();
  int nl = t >> 2, h = t & 3;       // 64 nodes x 4 heads
  float vs = 0.f, vd = 0.f;
  #pragma unroll
  for (int k = 0; k < 32; ++k) {
    float xv = sx[nl * 33 + k];
    vs += xv * sts[h * 32 + k];
    vd += xv * std_[h * 32 + k];
  }
  als[(n0 + nl) * 4 + h] = vs;
  ald[(n0 + nl) * 4 + h] = vd;
}

// ---------------- per-edge softmax weights (no max-sub: logits are O(1))
// layer 1: 4 heads -> float4
__global__ void edge_w4(const int* __restrict__ esrc, const int* __restrict__ edst,
                        const float* __restrict__ als, const float* __restrict__ ald,
                        float4* __restrict__ w4) {
  int j = blockIdx.x * 256 + threadIdx.x;   // j < ET
  int s = esrc[j], d = edst[j];
  float4 a = ((const float4*)als)[s];
  float4 b = ((const float4*)ald)[d];
  float e0 = a.x + b.x; e0 = (e0 > 0.f) ? e0 : 0.2f * e0;
  float e1 = a.y + b.y; e1 = (e1 > 0.f) ? e1 : 0.2f * e1;
  float e2 = a.z + b.z; e2 = (e2 > 0.f) ? e2 : 0.2f * e2;
  float e3 = a.w + b.w; e3 = (e3 > 0.f) ? e3 : 0.2f * e3;
  w4[j] = make_float4(__expf(e0), __expf(e1), __expf(e2), __expf(e3));
}

// layers 2/3: 1 head
__global__ void edge_w1(const int* __restrict__ esrc, const int* __restrict__ edst,
                        const float* __restrict__ als, const float* __restrict__ ald,
                        float* __restrict__ w) {
  int j = blockIdx.x * 256 + threadIdx.x;   // j < ET
  float e = als[esrc[j]] + ald[edst[j]];
  e = (e > 0.f) ? e : 0.2f * e;
  w[j] = __expf(e);
}

// ---------------- GAT1 pure aggregate: wave per node, NO LDS, no epilogue.
__global__ __launch_bounds__(256) void gat1_agg(
    const float* __restrict__ x, const int* __restrict__ offs,
    const int* __restrict__ esrc, const float4* __restrict__ w4arr,
    float* __restrict__ ya) {
  int t = threadIdx.x;
  int wv = t >> 6, lane = t & 63;
  int k = lane & 31, jp = lane >> 5;
  int n = blockIdx.x * 4 + wv;
  int start = offs[n], end = offs[n + 1];
  float xa0 = 0.f, xa1 = 0.f, xa2 = 0.f, xa3 = 0.f;
  float S0 = 0.f, S1 = 0.f, S2 = 0.f, S3 = 0.f;
  int j = start + jp;
  // unroll-2 over this parity's edges: 2 (esrc,w4,x) loads in flight
  for (; j + 2 < end; j += 4) {
    int sA_ = esrc[j], sB_ = esrc[j + 2];
    float4 wA = w4arr[j], wB = w4arr[j + 2];
    float xA = x[(size_t)sA_ * 32 + k];
    float xB = x[(size_t)sB_ * 32 + k];
    xa0 += wA.x * xA; xa1 += wA.y * xA; xa2 += wA.z * xA; xa3 += wA.w * xA;
    S0 += wA.x; S1 += wA.y; S2 += wA.z; S3 += wA.w;
    xa0 += wB.x * xB; xa1 += wB.y * xB; xa2 += wB.z * xB; xa3 += wB.w * xB;
    S0 += wB.x; S1 += wB.y; S2 += wB.z; S3 += wB.w;
  }
  if (j < end) {
    int s = esrc[j];
    float4 w = w4arr[j];
    float xv = x[(size_t)s * 32 + k];
    xa0 += w.x * xv; xa1 += w.y * xv; xa2 += w.z * xv; xa3 += w.w * xv;
    S0 += w.x; S1 += w.y; S2 += w.z; S3 += w.w;
  }
  // combine the two edge-parities
  xa0 += __shfl_xor(xa0, 32); S0 += __shfl_xor(S0, 32);
  xa1 += __shfl_xor(xa1, 32); S1 += __shfl_xor(S1, 32);
  xa2 += __shfl_xor(xa2, 32); S2 += __shfl_xor(S2, 32);
  xa3 += __shfl_xor(xa3, 32); S3 += __shfl_xor(S3, 32);
  // parity 0 writes heads 0,1; parity 1 writes heads 2,3 (128B each)
  if (jp == 0) {
    ya[(size_t)n * 128 +  0 + k] = xa0 / (S0 + 1e-16f);
    ya[(size_t)n * 128 + 32 + k] = xa1 / (S1 + 1e-16f);
  } else {
    ya[(size_t)n * 128 + 64 + k] = xa2 / (S2 + 1e-16f);
    ya[(size_t)n * 128 + 96 + k] = xa3 / (S3 + 1e-16f);
  }
}

// ---------------- fused GAT1-proj + GAT2-GEMM (agg1 never materialized):
// per 64-row block, per head-chunk kt (=head kt):
//   t1c[64][64] = relu(ya[:,kt*32:+32] @ W1[:,kt*64:+64] + b1[kt*64:+64])   (LDS)
//   acc += t1c @ W2[kt*64:+64, :]
// epilogue: h2 (raw) + als2/ald2.
__global__ __launch_bounds__(256) void gat2_fused(
    const float* __restrict__ ya, const float* __restrict__ W1,
    const float* __restrict__ b1, const float* __restrict__ W2,
    const float* __restrict__ a_s, const float* __restrict__ a_d,
    float* __restrict__ h2, float* __restrict__ als, float* __restrict__ ald) {
  __shared__ float sYa[64 * 36];     // ya chunk [64][32+pad4]   9.2 KB
  __shared__ float sT1[64 * 68];     // t1 chunk [64][64+pad4]  17.4 KB
  __shared__ float sW1c[32 * 64];    // W1 chunk                 8 KB
  __shared__ float sW2[64 * 64];     // W2 k-tile               16 KB
  int t = threadIdx.x;
  int row0 = blockIdx.x * 64;
  int cq = t & 15;                   // col quad (cols cq*4..+3 of 64)
  int rs = t >> 4;                   // row slot (rows rs*4..+3)
  float4 acc2[4];
  #pragma unroll
  for (int rp = 0; rp < 4; ++rp) acc2[rp] = make_float4(0.f, 0.f, 0.f, 0.f);
  for (int kt = 0; kt < 4; ++kt) {
    if (kt > 0) __syncthreads();     // prev phase-B done before overwriting LDS
    #pragma unroll
    for (int j = 0; j < 2; ++j) {    // stage ya chunk [64][32]
      int li = t + j * 256;
      int r = li >> 3, f4i = li & 7;
      *(float4*)&sYa[r * 36 + f4i * 4] =
          *(const float4*)&ya[(size_t)(row0 + r) * 128 + kt * 32 + f4i * 4];
    }
    #pragma unroll
    for (int j = 0; j < 2; ++j) {    // stage W1 chunk [32][64]
      int li = t + j * 256;
      int kk = li >> 4, cc = (li & 15) * 4;
      *(float4*)&sW1c[kk * 64 + cc] =
          *(const float4*)&W1[(size_t)kk * 256 + kt * 64 + cc];
    }
    #pragma unroll
    for (int j = 0; j < 4; ++j) {    // stage W2 k-tile [64][64]
      int li = t + j * 256;
      int kk = li >> 4, cc = (li & 15) * 4;
      *(float4*)&sW2[kk * 64 + cc] =
          *(const float4*)&W2[(size_t)(kt * 64 + kk) * 64 + cc];
    }
    __syncthreads();
    // phase A: t1c = relu(yaC @ W1c + b1c)
    float4 acc1[4];
    #pragma unroll
    for (int rp = 0; rp < 4; ++rp) acc1[rp] = make_float4(0.f, 0.f, 0.f, 0.f);
    #pragma unroll
    for (int kq = 0; kq < 8; ++kq) {
      float4 a4[4];
      #pragma unroll
      for (int rp = 0; rp < 4; ++rp)
        a4[rp] = *(const float4*)&sYa[(rs * 4 + rp) * 36 + kq * 4];
      #pragma unroll
      for (int i = 0; i < 4; ++i) {
        float4 w4 = *(const float4*)&sW1c[(kq * 4 + i) * 64 + cq * 4];
        #pragma unroll
        for (int rp = 0; rp < 4; ++rp) {
          float a = (i == 0) ? a4[rp].x : (i == 1) ? a4[rp].y
                  : (i == 2) ? a4[rp].z : a4[rp].w;
          acc1[rp].x += a * w4.x; acc1[rp].y += a * w4.y;
          acc1[rp].z += a * w4.z; acc1[rp].w += a * w4.w;
        }
      }
    }
    float4 b4 = *(const float4*)&b1[kt * 64 + cq * 4];
    #pragma unroll
    for (int rp = 0; rp < 4; ++rp) {
      float4 v = acc1[rp];
      v.x = fmaxf(v.x + b4.x, 0.f); v.y = fmaxf(v.y + b4.y, 0.f);
      v.z = fmaxf(v.z + b4.z, 0.f); v.w = fmaxf(v.w + b4.w, 0.f);
      *(float4*)&sT1[(rs * 4 + rp) * 68 + cq * 4] = v;
    }
    __syncthreads();
    // phase B: acc2 += t1c @ W2tile
    #pragma unroll
    for (int kq = 0; kq < 16; ++kq) {
      float4 a4[4];
      #pragma unroll
      for (int rp = 0; rp < 4; ++rp)
        a4[rp] = *(const float4*)&sT1[(rs * 4 + rp) * 68 + kq * 4];
      #pragma unroll
      for (int i = 0; i < 4; ++i) {
        float4 w4 = *(const float4*)&sW2[(kq * 4 + i) * 64 + cq * 4];
        #pragma unroll
        for (int rp = 0; rp < 4; ++rp) {
          float a = (i == 0) ? a4[rp].x : (i == 1) ? a4[rp].y
                  : (i == 2) ? a4[rp].z : a4[rp].w;
          acc2[rp].x += a * w4.x; acc2[rp].y += a * w4.y;
          acc2[rp].z += a * w4.z; acc2[rp].w += a * w4.w;
        }
      }
    }
  }
  // epilogue: raw h2 + als2/ald2
  float4 s4 = *(const float4*)&a_s[cq * 4];
  float4 d4 = *(const float4*)&a_d[cq * 4];
  #pragma unroll
  for (int rp = 0; rp < 4; ++rp) {
    int r = row0 + rs * 4 + rp;
    *(float4*)&h2[(size_t)r * 64 + cq * 4] = acc2[rp];
    float vs = acc2[rp].x * s4.x + acc2[rp].y * s4.y + acc2[rp].z * s4.z + acc2[rp].w * s4.w;
    float vd = acc2[rp].x * d4.x + acc2[rp].y * d4.y + acc2[rp].z * d4.z + acc2[rp].w * d4.w;
    #pragma unroll
    for (int o = 8; o >= 1; o >>= 1) { vs += __shfl_xor(vs, o); vd += __shfl_xor(vd, o); }
    if (cq == 0) { als[r] = vs; ald[r] = vd; }
  }
}

// ---------------- float4 register-tiled GEMM: A[M,K] @ W[K,64]
template <int KTILES, int ROWS, bool AL>
__global__ __launch_bounds__(256) void gemm_n64(
    const float* __restrict__ A, const float* __restrict__ W,
    const float* __restrict__ bias, const float* __restrict__ a_s,
    const float* __restrict__ a_d, float* __restrict__ out,
    float* __restrict__ als, float* __restrict__ ald) {
  constexpr int K = KTILES * 64;
  constexpr int RPT = ROWS / 16;       // rows per thread
  constexpr int SAS = 68;              // sA stride: 16B-aligned, bank-staggered
  __shared__ float sW[64 * 64];        // [k][c] 16 KB
  __shared__ float sA[ROWS * SAS];
  int t = threadIdx.x;
  int cq = t & 15;
  int rs = t >> 4;
  int row0 = blockIdx.x * ROWS;
  float4 acc[RPT];
  #pragma unroll
  for (int rp = 0; rp < RPT; ++rp) acc[rp] = make_float4(0.f, 0.f, 0.f, 0.f);
  for (int kt = 0; kt < KTILES; ++kt) {
    #pragma unroll
    for (int j = 0; j < 4; ++j) {      // stage W tile [64][64]
      int li = t + j * 256;
      int kk = li >> 4, cc = (li & 15) * 4;
      *(float4*)&sW[kk * 64 + cc] =
          *(const float4*)&W[(size_t)(kt * 64 + kk) * 64 + cc];
    }
    #pragma unroll
    for (int j = 0; j < ROWS / 16; ++j) {  // stage A tile [ROWS][64]
      int li = t + j * 256;
      int r = li >> 4, kkq = (li & 15) * 4;
      *(float4*)&sA[r * SAS + kkq] =
          *(const float4*)&A[(size_t)(row0 + r) * K + kt * 64 + kkq];
    }
    __syncthreads();
    #pragma unroll
    for (int kq = 0; kq < 16; ++kq) {
      float4 a4[RPT];
      #pragma unroll
      for (int rp = 0; rp < RPT; ++rp)
        a4[rp] = *(const float4*)&sA[(rs * RPT + rp) * SAS + kq * 4];
      #pragma unroll
      for (int i = 0; i < 4; ++i) {
        float4 w4 = *(const float4*)&sW[(kq * 4 + i) * 64 + cq * 4];
        #pragma unroll
        for (int rp = 0; rp < RPT; ++rp) {
          float a = (i == 0) ? a4[rp].x : (i == 1) ? a4[rp].y
                  : (i == 2) ? a4[rp].z : a4[rp].w;
          acc[rp].x += a * w4.x; acc[rp].y += a * w4.y;
          acc[rp].z += a * w4.z; acc[rp].w += a * w4.w;
        }
      }
    }
    __syncthreads();
  }
  #pragma unroll
  for (int rp = 0; rp < RPT; ++rp) {
    int r = row0 + rs * RPT + rp;
    if constexpr (AL) {
      *(float4*)&out[(size_t)r * 64 + cq * 4] = acc[rp];   // raw h
      float4 s4 = *(const float4*)&a_s[cq * 4];
      float4 d4 = *(const float4*)&a_d[cq * 4];
      float vs = acc[rp].x * s4.x + acc[rp].y * s4.y + acc[rp].z * s4.z + acc[rp].w * s4.w;
      float vd = acc[rp].x * d4.x + acc[rp].y * d4.y + acc[rp].z * d4.z + acc[rp].w * d4.w;
      #pragma unroll
      for (int o = 8; o >= 1; o >>= 1) { vs += __shfl_xor(vs, o); vd += __shfl_xor(vd, o); }
      if (cq == 0) { als[r] = vs; ald[r] = vd; }
    } else {
      float4 b4 = *(const float4*)&bias[cq * 4];
      float4 v = acc[rp];
      v.x = fmaxf(v.x + b4.x, 0.f); v.y = fmaxf(v.y + b4.y, 0.f);
      v.z = fmaxf(v.z + b4.z, 0.f); v.w = fmaxf(v.w + b4.w, 0.f);
      *(float4*)&out[(size_t)r * 64 + cq * 4] = v;
    }
  }
}

// ---------------- fc1 split-K: part[sp][row][c] = A[row, sp*128:+128]·W[sp*128:+128, c]
__global__ __launch_bounds__(256) void gemm_fc1_split(
    const float* __restrict__ A, const float* __restrict__ W,
    float* __restrict__ part) {
  __shared__ float sW[128 * 64];     // 32 KB
  __shared__ float sA[16 * 132];     // 16 rows x 128 k, padded stride
  int t = threadIdx.x;
  int bid = blockIdx.x;
  int rt = bid >> 5;                 // row tile (0..127)
  int sp = bid & 31;                 // k-split  (0..31)
  #pragma unroll
  for (int j = 0; j < 8; ++j) {      // stage W chunk [128][64]
    int li = t + j * 256;
    int kk = li >> 4, cc = (li & 15) * 4;
    *(float4*)&sW[kk * 64 + cc] =
        *(const float4*)&W[(size_t)(sp * 128 + kk) * 64 + cc];
  }
  #pragma unroll
  for (int j = 0; j < 2; ++j) {      // stage A tile [16][128]
    int li = t + j * 256;
    int r = li >> 5, kq4 = (li & 31) * 4;
    *(float4*)&sA[r * 132 + kq4] =
        *(const float4*)&A[(size_t)(rt * 16 + r) * 4096 + sp * 128 + kq4];
  }
  __syncthreads();
  int cq = t & 15;                   // col quad
  int rs = t >> 4;                   // row slot (0..15)
  float4 acc = make_float4(0.f, 0.f, 0.f, 0.f);
  #pragma unroll
  for (int kq = 0; kq < 32; ++kq) {
    float4 a4 = *(const float4*)&sA[rs * 132 + kq * 4];
    #pragma unroll
    for (int i = 0; i < 4; ++i) {
      float4 w4 = *(const float4*)&sW[(kq * 4 + i) * 64 + cq * 4];
      float a = (i == 0) ? a4.x : (i == 1) ? a4.y : (i == 2) ? a4.z : a4.w;
      acc.x += a * w4.x; acc.y += a * w4.y; acc.z += a * w4.z; acc.w += a * w4.w;
    }
  }
  *(float4*)&part[((size_t)sp * BB + rt * 16 + rs) * 64 + cq * 4] = acc;
}

// ---------------- H=1 aggregate with precomputed weights + bias + relu
__global__ __launch_bounds__(256) void gat_aggregate(
    const float* __restrict__ hsrc, const float* __restrict__ warr,
    const int* __restrict__ offs, const int* __restrict__ esrc,
    const float* __restrict__ bias, float* __restrict__ out) {
  int wv = threadIdx.x >> 6;
  int lane = threadIdx.x & 63;
  int n = blockIdx.x * 4 + wv;
  int start = offs[n], end = offs[n + 1];
  float acc = 0.f, S = 0.f;
  int j = start;
  for (; j + 4 <= end; j += 4) {          // 4 gathers in flight
    int s0 = esrc[j], s1 = esrc[j+1], s2 = esrc[j+2], s3 = esrc[j+3];
    float w0 = warr[j], w1 = warr[j+1], w2 = warr[j+2], w3 = warr[j+3];
    float v0 = hsrc[(size_t)s0 * 64 + lane];
    float v1 = hsrc[(size_t)s1 * 64 + lane];
    float v2 = hsrc[(size_t)s2 * 64 + lane];
    float v3 = hsrc[(size_t)s3 * 64 + lane];
    acc += w0 * v0; acc += w1 * v1; acc += w2 * v2; acc += w3 * v3;
    S += w0 + w1 + w2 + w3;
  }
  for (; j < end; ++j) {
    int s = esrc[j]; float w = warr[j];
    acc += w * hsrc[(size_t)s * 64 + lane];
    S += w;
  }
  float v = acc / (S + 1e-16f) + bias[lane];
  out[(size_t)n * 64 + lane] = fmaxf(v, 0.f);
}

// ---------------- fused fc1-reduce + fc2 + fc3 + softmax, one wave per batch row
__global__ __launch_bounds__(256) void fc23_softmax(
    const float* __restrict__ part, const float* __restrict__ fcb1,
    const float* __restrict__ W2, const float* __restrict__ b2,
    const float* __restrict__ W3, const float* __restrict__ b3,
    float* __restrict__ out) {
  int ws = threadIdx.x >> 6;
  int row = blockIdx.x * 4 + ws;
  int lane = threadIdx.x & 63;
  __shared__ float sh1[4][64];
  __shared__ float sh2[4][32];
  // reduce the 32 k-split partials for h1[row][lane] (coalesced 256B per sp)
  float h1 = fcb1[lane];
  #pragma unroll
  for (int sp = 0; sp < KSPLIT; sp += 4) {
    float p0 = part[((size_t)(sp + 0) * BB + row) * 64 + lane];
    float p1 = part[((size_t)(sp + 1) * BB + row) * 64 + lane];
    float p2 = part[((size_t)(sp + 2) * BB + row) * 64 + lane];
    float p3 = part[((size_t)(sp + 3) * BB + row) * 64 + lane];
    h1 += p0 + p1 + p2 + p3;
  }
  sh1[ws][lane] = fmaxf(h1, 0.f);     // wave-local: no barrier
  if (lane < 32) {
    float acc = b2[lane];
    #pragma unroll
    for (int k = 0; k < 64; ++k) acc += sh1[ws][k] * W2[k * 32 + lane];
    sh2[ws][lane] = fmaxf(acc, 0.f);  // wave-local
  }
  float logit = -INFINITY;
  if (lane < 16) {
    float acc = b3[lane];
    #pragma unroll
    for (int k = 0; k < 32; ++k) acc += sh2[ws][k] * W3[k * 16 + lane];
    logit = acc;
  }
  float mx = logit;
  #pragma unroll
  for (int o = 8; o >= 1; o >>= 1) mx = fmaxf(mx, __shfl_xor(mx, o));
  float ex = (lane < 16) ? __expf(logit - mx) : 0.f;
  float ssum = ex;
  #pragma unroll
  for (int o = 8; o >= 1; o >>= 1) ssum += __shfl_xor(ssum, o);
  if (lane < 16) out[row * 16 + lane] = ex / ssum;
}

// ---------------- launcher ----------------
extern "C" void kernel_launch(void* const* d_in, const int* in_sizes, int n_in,
                              void* d_out, int out_size, void* d_ws, size_t ws_size,
                              hipStream_t stream) {
  const float* x0   = (const float*)d_in[0];
  const int*   ei   = (const int*)d_in[1];
  const float* W1   = (const float*)d_in[2];
  const float* a1s  = (const float*)d_in[3];
  const float* a1d  = (const float*)d_in[4];
  const float* b1   = (const float*)d_in[5];
  const float* W2   = (const float*)d_in[6];
  const float* a2s  = (const float*)d_in[7];
  const float* a2d  = (const float*)d_in[8];
  const float* b2   = (const float*)d_in[9];
  const float* W3   = (const float*)d_in[10];
  const float* a3s  = (const float*)d_in[11];
  const float* a3d  = (const float*)d_in[12];
  const float* b3   = (const float*)d_in[13];
  const float* fcW1 = (const float*)d_in[14];
  const float* fcb1 = (const float*)d_in[15];
  const float* fcW2 = (const float*)d_in[16];
  const float* fcb2 = (const float*)d_in[17];
  const float* fcW3 = (const float*)d_in[18];
  const float* fcb3 = (const float*)d_in[19];
  float* out = (float*)d_out;

  // workspace layout (~214 MB)
  float* agg1   = (float*)d_ws;                       // [N*256] scratch region (33.5M floats)
  float* h23    = agg1 + (size_t)NN * 256;            // [N*64]
  float* agg23  = h23 + (size_t)NN * 64;              // [N*64]
  float* als1   = agg23 + (size_t)NN * 64;            // [N*4]
  float* ald1   = als1 + (size_t)NN * 4;              // [N*4]
  float* als2   = ald1 + (size_t)NN * 4;              // [N]
  float* ald2   = als2 + NN;                          // [N]
  float* wts    = ald2 + NN;                          // [128]
  float* wtd    = wts + 128;                          // [128]
  int*   counts = (int*)(wtd + 128);                  // [N]
  int*   offs   = counts + NN;                        // [N+1]
  int*   cursor = offs + NN + 1;                      // [N]
  int*   esrc   = cursor + NN;                        // [ET]
  int*   edst   = esrc + ET;                          // [ET]
  int*   blksums= edst + ET;                          // [512]
  // overlays inside the agg1 scratch region (no agg1 tensor anymore):
  float4* w41   = (float4*)agg1;                      // [ET] f4 (0 .. 2.62M fl), dead after gat1_agg
  float* h2     = agg1 + ((size_t)4 << 20);           // [N*64] (4M .. 12.4M fl)
  float* als3   = agg1 + ((size_t)13 << 20);          // [N]
  float* ald3   = als3 + NN;                          // [N]
  float* w2     = agg1 + ((size_t)14 << 20);          // [ET]
  float* w3arr  = w2 + ET;                            // [ET]
  float* part   = agg1 + ((size_t)16 << 20);          // [KSPLIT*B*64] = 4.2M fl
  float* ya     = h23;                                // [N*128] spans h23+agg23 (dead after gat2_fused)

  // CSR build (reused by all 3 GAT layers)
  init_counts<<<NN / 256, 256, 0, stream>>>(counts);
  count_edges<<<EE / 256, 256, 0, stream>>>(ei, counts);
  scan_block<<<NN / 256, 256, 0, stream>>>(counts, offs, blksums);
  scan_sums<<<1, 512, 0, stream>>>(blksums);
  scan_add<<<NN / 256, 256, 0, stream>>>(offs, cursor, blksums);
  fill_csr<<<ET / 256, 256, 0, stream>>>(ei, cursor, esrc, edst);

  // GAT1: logits via tiny projections; per-edge weights; pure aggregate
  l1_avec<<<1, 128, 0, stream>>>(W1, a1s, a1d, wts, wtd);
  l1_logits<<<NN / 64, 256, 0, stream>>>(x0, wts, wtd, als1, ald1);
  edge_w4<<<ET / 256, 256, 0, stream>>>(esrc, edst, als1, ald1, w41);
  gat1_agg<<<NN / 4, 256, 0, stream>>>(x0, offs, esrc, w41, ya);
  // fused GAT1-proj + GAT2-GEMM: ya -> h2 + als2/ald2 (agg1 never materialized)
  gat2_fused<<<NN / 64, 256, 0, stream>>>(ya, W1, b1, W2, a2s, a2d, h2, als2, ald2);
  edge_w1<<<ET / 256, 256, 0, stream>>>(esrc, edst, als2, ald2, w2);
  // GAT2 aggregate -> agg2 (bias+relu)
  gat_aggregate<<<NN / 4, 256, 0, stream>>>(h2, w2, offs, esrc, b2, agg23);
  // GAT3 GEMM: [N,64]@[64,64] -> h3 + als3/ald3
  gemm_n64<1, 64, true><<<NN / 64, 256, 0, stream>>>(agg23, W3, nullptr, a3s, a3d, h23, als3, ald3);
  edge_w1<<<ET / 256, 256, 0, stream>>>(esrc, edst, als3, ald3, w3arr);
  // GAT3 aggregate -> agg3
  gat_aggregate<<<NN / 4, 256, 0, stream>>>(h23, w3arr, offs, esrc, b3, agg23);
  // actor MLP: split-K fc1 partials, then fused reduce+fc2+fc3+softmax
  gemm_fc1_split<<<128 * KSPLIT, 256, 0, stream>>>(agg23, fcW1, part);
  fc23_softmax<<<BB / 4, 256, 0, stream>>>(part, fcb1, fcW2, fcb2, fcW3, fcb3, out);
}

// Round 15
// 490.413 us; speedup vs baseline: 1.5347x; 1.0171x over previous
//
#include <hip/hip_runtime.h>
#include <math.h>

#define NN 131072            // total nodes
#define FF 32                // input features
#define EE 524288            // random edges
#define ET (EE + NN)         // edges + self loops = 655360
#define BB 2048              // batch (graphs)
#define KSPLIT 32            // fc1 K-split (4096 / 128)

// ---------------- CSR build (counting sort by dst) ----------------
__global__ void init_counts(int* counts) {
  int i = blockIdx.x * 256 + threadIdx.x;
  counts[i] = 1;                       // self loop contributes 1 per node
}

__global__ void count_edges(const int* __restrict__ ei, int* counts) {
  int e = blockIdx.x * 256 + threadIdx.x;
  atomicAdd(&counts[ei[EE + e]], 1);   // dst row of edge_index
}

__global__ void scan_block(const int* __restrict__ counts, int* offs, int* blksums) {
  __shared__ int sd[256];
  int t = threadIdx.x;
  int i = blockIdx.x * 256 + t;
  int v = counts[i];
  sd[t] = v;
  __syncthreads();
  for (int o = 1; o < 256; o <<= 1) {
    int x = (t >= o) ? sd[t - o] : 0;
    __syncthreads();
    sd[t] += x;
    __syncthreads();
  }
  offs[i] = sd[t] - v;                 // block-local exclusive scan
  if (t == 255) blksums[blockIdx.x] = sd[255];
}

__global__ void scan_sums(int* blksums) {  // 1 block x 512 threads
  __shared__ int sd[512];
  int t = threadIdx.x;
  int v = blksums[t];
  sd[t] = v;
  __syncthreads();
  for (int o = 1; o < 512; o <<= 1) {
    int x = (t >= o) ? sd[t - o] : 0;
    __syncthreads();
    sd[t] += x;
    __syncthreads();
  }
  blksums[t] = sd[t] - v;              // exclusive scan of block sums
}

__global__ void scan_add(int* offs, int* cursor, const int* __restrict__ blksums) {
  int i = blockIdx.x * 256 + threadIdx.x;
  int o = offs[i] + blksums[blockIdx.x];
  offs[i] = o;
  cursor[i] = o;
  if (i == 0) offs[NN] = ET;
}

__global__ void fill_csr(const int* __restrict__ ei, int* cursor,
                         int* esrc, int* edst) {
  int i = blockIdx.x * 256 + threadIdx.x;   // i < ET
  int s, d;
  if (i < EE) { s = ei[i]; d = ei[EE + i]; }
  else        { s = d = i - EE; }           // self loop
  int pos = atomicAdd(&cursor[d], 1);
  esrc[pos] = s;
  edst[pos] = d;
}

// ---------------- layer-1 attention vectors: wts[h,k] = sum_c W1[k,h*64+c]*a1s[h,c]
__global__ void l1_avec(const float* __restrict__ W1, const float* __restrict__ a1s,
                        const float* __restrict__ a1d, float* __restrict__ wts,
                        float* __restrict__ wtd) {
  int t = threadIdx.x;          // 128 threads: h = t>>5, k = t&31
  int h = t >> 5, k = t & 31;
  float as = 0.f, ad = 0.f;
  #pragma unroll
  for (int c = 0; c < 64; ++c) {
    float w = W1[k * 256 + h * 64 + c];
    as += w * a1s[h * 64 + c];
    ad += w * a1d[h * 64 + c];
  }
  wts[t] = as;
  wtd[t] = ad;
}

// ---------------- layer-1 logits: als[n,h] = x[n]·wts[h]  (64 nodes / block)
__global__ __launch_bounds__(256) void l1_logits(
    const float* __restrict__ x, const float* __restrict__ wts,
    const float* __restrict__ wtd, float* __restrict__ als, float* __restrict__ ald) {
  __shared__ float sx[64 * 33];     // padded stride 33: kill bank conflicts
  __shared__ float sts[128], std_[128];
  int t = threadIdx.x;
  int n0 = blockIdx.x * 64;
  #pragma unroll
  for (int j = 0; j < 8; ++j) {
    int idx = t + j * 256;          // 0..2047
    sx[(idx >> 5) * 33 + (idx & 31)] = x[(size_t)n0 * 32 + idx];
  }
  if (t < 128) sts[t] = wts[t]; else std_[t - 128] = wtd[t - 128];
  __syncthreads();
  int nl = t >> 2, h = t & 3;       // 64 nodes x 4 heads
  float vs = 0.f, vd = 0.f;
  #pragma unroll
  for (int k = 0; k < 32; ++k) {
    float xv = sx[nl * 33 + k];
    vs += xv * sts[h * 32 + k];
    vd += xv * std_[h * 32 + k];
  }
  als[(n0 + nl) * 4 + h] = vs;
  ald[(n0 + nl) * 4 + h] = vd;
}

// ---------------- per-edge softmax weights (no max-sub: logits are O(1))
// layer 1: 4 heads -> float4
__global__ void edge_w4(const int* __restrict__ esrc, const int* __restrict__ edst,
                        const float* __restrict__ als, const float* __restrict__ ald,
                        float4* __restrict__ w4) {
  int j = blockIdx.x * 256 + threadIdx.x;   // j < ET
  int s = esrc[j], d = edst[j];
  float4 a = ((const float4*)als)[s];
  float4 b = ((const float4*)ald)[d];
  float e0 = a.x + b.x; e0 = (e0 > 0.f) ? e0 : 0.2f * e0;
  float e1 = a.y + b.y; e1 = (e1 > 0.f) ? e1 : 0.2f * e1;
  float e2 = a.z + b.z; e2 = (e2 > 0.f) ? e2 : 0.2f * e2;
  float e3 = a.w + b.w; e3 = (e3 > 0.f) ? e3 : 0.2f * e3;
  w4[j] = make_float4(__expf(e0), __expf(e1), __expf(e2), __expf(e3));
}

// layers 2/3: 1 head
__global__ void edge_w1(const int* __restrict__ esrc, const int* __restrict__ edst,
                        const float* __restrict__ als, const float* __restrict__ ald,
                        float* __restrict__ w) {
  int j = blockIdx.x * 256 + threadIdx.x;   // j < ET
  float e = als[esrc[j]] + ald[edst[j]];
  e = (e > 0.f) ? e : 0.2f * e;
  w[j] = __expf(e);
}

// ---------------- GAT1 pure aggregate: wave per node, NO LDS, no epilogue.
__global__ __launch_bounds__(256) void gat1_agg(
    const float* __restrict__ x, const int* __restrict__ offs,
    const int* __restrict__ esrc, const float4* __restrict__ w4arr,
    float* __restrict__ ya) {
  int t = threadIdx.x;
  int wv = t >> 6, lane = t & 63;
  int k = lane & 31, jp = lane >> 5;
  int n = blockIdx.x * 4 + wv;
  int start = offs[n], end = offs[n + 1];
  float xa0 = 0.f, xa1 = 0.f, xa2 = 0.f, xa3 = 0.f;
  float S0 = 0.f, S1 = 0.f, S2 = 0.f, S3 = 0.f;
  int j = start + jp;
  // unroll-2 over this parity's edges: 2 (esrc,w4,x) loads in flight
  for (; j + 2 < end; j += 4) {
    int sA_ = esrc[j], sB_ = esrc[j + 2];
    float4 wA = w4arr[j], wB = w4arr[j + 2];
    float xA = x[(size_t)sA_ * 32 + k];
    float xB = x[(size_t)sB_ * 32 + k];
    xa0 += wA.x * xA; xa1 += wA.y * xA; xa2 += wA.z * xA; xa3 += wA.w * xA;
    S0 += wA.x; S1 += wA.y; S2 += wA.z; S3 += wA.w;
    xa0 += wB.x * xB; xa1 += wB.y * xB; xa2 += wB.z * xB; xa3 += wB.w * xB;
    S0 += wB.x; S1 += wB.y; S2 += wB.z; S3 += wB.w;
  }
  if (j < end) {
    int s = esrc[j];
    float4 w = w4arr[j];
    float xv = x[(size_t)s * 32 + k];
    xa0 += w.x * xv; xa1 += w.y * xv; xa2 += w.z * xv; xa3 += w.w * xv;
    S0 += w.x; S1 += w.y; S2 += w.z; S3 += w.w;
  }
  // combine the two edge-parities
  xa0 += __shfl_xor(xa0, 32); S0 += __shfl_xor(S0, 32);
  xa1 += __shfl_xor(xa1, 32); S1 += __shfl_xor(S1, 32);
  xa2 += __shfl_xor(xa2, 32); S2 += __shfl_xor(S2, 32);
  xa3 += __shfl_xor(xa3, 32); S3 += __shfl_xor(S3, 32);
  // parity 0 writes heads 0,1; parity 1 writes heads 2,3 (128B each)
  if (jp == 0) {
    ya[(size_t)n * 128 +  0 + k] = xa0 / (S0 + 1e-16f);
    ya[(size_t)n * 128 + 32 + k] = xa1 / (S1 + 1e-16f);
  } else {
    ya[(size_t)n * 128 + 64 + k] = xa2 / (S2 + 1e-16f);
    ya[(size_t)n * 128 + 96 + k] = xa3 / (S3 + 1e-16f);
  }
}

// ---------------- fused GAT1-proj + GAT2-GEMM (agg1 never materialized):
// per 64-row block, per head-chunk kt (=head kt):
//   t1c[64][64] = relu(ya[:,kt*32:+32] @ W1[:,kt*64:+64] + b1[kt*64:+64])   (LDS)
//   acc += t1c @ W2[kt*64:+64, :]
// LDS UNION: {sYa[64*36] | sW1c[32*64]} (phase A) aliases sT1[64][68]
// (phase B) — 4352 floats exactly. 33.4 KB total -> 4 blocks/CU (was 50.6/3).
__global__ __launch_bounds__(256) void gat2_fused(
    const float* __restrict__ ya, const float* __restrict__ W1,
    const float* __restrict__ b1, const float* __restrict__ W2,
    const float* __restrict__ a_s, const float* __restrict__ a_d,
    float* __restrict__ h2, float* __restrict__ als, float* __restrict__ ald) {
  __shared__ float uni[64 * 68];     // 17.4 KB union
  __shared__ float sW2[64 * 64];     // W2 k-tile 16 KB
  float* sYa  = uni;                 // [64][36]  (phase A)
  float* sW1c = uni + 64 * 36;       // [32][64]  (phase A)
  float* sT1  = uni;                 // [64][68]  (phase B)
  int t = threadIdx.x;
  int row0 = blockIdx.x * 64;
  int cq = t & 15;                   // col quad (cols cq*4..+3 of 64)
  int rs = t >> 4;                   // row slot (rows rs*4..+3)
  float4 acc2[4];
  #pragma unroll
  for (int rp = 0; rp < 4; ++rp) acc2[rp] = make_float4(0.f, 0.f, 0.f, 0.f);
  for (int kt = 0; kt < 4; ++kt) {
    if (kt > 0) __syncthreads();     // prev phase-B done reading uni/sW2
    #pragma unroll
    for (int j = 0; j < 2; ++j) {    // stage ya chunk [64][32]
      int li = t + j * 256;
      int r = li >> 3, f4i = li & 7;
      *(float4*)&sYa[r * 36 + f4i * 4] =
          *(const float4*)&ya[(size_t)(row0 + r) * 128 + kt * 32 + f4i * 4];
    }
    #pragma unroll
    for (int j = 0; j < 2; ++j) {    // stage W1 chunk [32][64]
      int li = t + j * 256;
      int kk = li >> 4, cc = (li & 15) * 4;
      *(float4*)&sW1c[kk * 64 + cc] =
          *(const float4*)&W1[(size_t)kk * 256 + kt * 64 + cc];
    }
    #pragma unroll
    for (int j = 0; j < 4; ++j) {    // stage W2 k-tile [64][64]
      int li = t + j * 256;
      int kk = li >> 4, cc = (li & 15) * 4;
      *(float4*)&sW2[kk * 64 + cc] =
          *(const float4*)&W2[(size_t)(kt * 64 + kk) * 64 + cc];
    }
    __syncthreads();
    // phase A: acc1 = yaC @ W1c (registers)
    float4 acc1[4];
    #pragma unroll
    for (int rp = 0; rp < 4; ++rp) acc1[rp] = make_float4(0.f, 0.f, 0.f, 0.f);
    #pragma unroll
    for (int kq = 0; kq < 8; ++kq) {
      float4 a4[4];
      #pragma unroll
      for (int rp = 0; rp < 4; ++rp)
        a4[rp] = *(const float4*)&sYa[(rs * 4 + rp) * 36 + kq * 4];
      #pragma unroll
      for (int i = 0; i < 4; ++i) {
        float4 w4 = *(const float4*)&sW1c[(kq * 4 + i) * 64 + cq * 4];
        #pragma unroll
        for (int rp = 0; rp < 4; ++rp) {
          float a = (i == 0) ? a4[rp].x : (i == 1) ? a4[rp].y
                  : (i == 2) ? a4[rp].z : a4[rp].w;
          acc1[rp].x += a * w4.x; acc1[rp].y += a * w4.y;
          acc1[rp].z += a * w4.z; acc1[rp].w += a * w4.w;
        }
      }
    }
    __syncthreads();                 // all reads of sYa/sW1c complete
    // write t1c = relu(acc1 + b1c) into the union (now sT1)
    float4 b4 = *(const float4*)&b1[kt * 64 + cq * 4];
    #pragma unroll
    for (int rp = 0; rp < 4; ++rp) {
      float4 v = acc1[rp];
      v.x = fmaxf(v.x + b4.x, 0.f); v.y = fmaxf(v.y + b4.y, 0.f);
      v.z = fmaxf(v.z + b4.z, 0.f); v.w = fmaxf(v.w + b4.w, 0.f);
      *(float4*)&sT1[(rs * 4 + rp) * 68 + cq * 4] = v;
    }
    __syncthreads();
    // phase B: acc2 += t1c @ W2tile
    #pragma unroll
    for (int kq = 0; kq < 16; ++kq) {
      float4 a4[4];
      #pragma unroll
      for (int rp = 0; rp < 4; ++rp)
        a4[rp] = *(const float4*)&sT1[(rs * 4 + rp) * 68 + kq * 4];
      #pragma unroll
      for (int i = 0; i < 4; ++i) {
        float4 w4 = *(const float4*)&sW2[(kq * 4 + i) * 64 + cq * 4];
        #pragma unroll
        for (int rp = 0; rp < 4; ++rp) {
          float a = (i == 0) ? a4[rp].x : (i == 1) ? a4[rp].y
                  : (i == 2) ? a4[rp].z : a4[rp].w;
          acc2[rp].x += a * w4.x; acc2[rp].y += a * w4.y;
          acc2[rp].z += a * w4.z; acc2[rp].w += a * w4.w;
        }
      }
    }
  }
  // epilogue: raw h2 + als2/ald2
  float4 s4 = *(const float4*)&a_s[cq * 4];
  float4 d4 = *(const float4*)&a_d[cq * 4];
  #pragma unroll
  for (int rp = 0; rp < 4; ++rp) {
    int r = row0 + rs * 4 + rp;
    *(float4*)&h2[(size_t)r * 64 + cq * 4] = acc2[rp];
    float vs = acc2[rp].x * s4.x + acc2[rp].y * s4.y + acc2[rp].z * s4.z + acc2[rp].w * s4.w;
    float vd = acc2[rp].x * d4.x + acc2[rp].y * d4.y + acc2[rp].z * d4.z + acc2[rp].w * d4.w;
    #pragma unroll
    for (int o = 8; o >= 1; o >>= 1) { vs += __shfl_xor(vs, o); vd += __shfl_xor(vd, o); }
    if (cq == 0) { als[r] = vs; ald[r] = vd; }
  }
}

// ---------------- float4 register-tiled GEMM: A[M,K] @ W[K,64]
template <int KTILES, int ROWS, bool AL>
__global__ __launch_bounds__(256) void gemm_n64(
    const float* __restrict__ A, const float* __restrict__ W,
    const float* __restrict__ bias, const float* __restrict__ a_s,
    const float* __restrict__ a_d, float* __restrict__ out,
    float* __restrict__ als, float* __restrict__ ald) {
  constexpr int K = KTILES * 64;
  constexpr int RPT = ROWS / 16;       // rows per thread
  constexpr int SAS = 68;              // sA stride: 16B-aligned, bank-staggered
  __shared__ float sW[64 * 64];        // [k][c] 16 KB
  __shared__ float sA[ROWS * SAS];
  int t = threadIdx.x;
  int cq = t & 15;
  int rs = t >> 4;
  int row0 = blockIdx.x * ROWS;
  float4 acc[RPT];
  #pragma unroll
  for (int rp = 0; rp < RPT; ++rp) acc[rp] = make_float4(0.f, 0.f, 0.f, 0.f);
  for (int kt = 0; kt < KTILES; ++kt) {
    #pragma unroll
    for (int j = 0; j < 4; ++j) {      // stage W tile [64][64]
      int li = t + j * 256;
      int kk = li >> 4, cc = (li & 15) * 4;
      *(float4*)&sW[kk * 64 + cc] =
          *(const float4*)&W[(size_t)(kt * 64 + kk) * 64 + cc];
    }
    #pragma unroll
    for (int j = 0; j < ROWS / 16; ++j) {  // stage A tile [ROWS][64]
      int li = t + j * 256;
      int r = li >> 4, kkq = (li & 15) * 4;
      *(float4*)&sA[r * SAS + kkq] =
          *(const float4*)&A[(size_t)(row0 + r) * K + kt * 64 + kkq];
    }
    __syncthreads();
    #pragma unroll
    for (int kq = 0; kq < 16; ++kq) {
      float4 a4[RPT];
      #pragma unroll
      for (int rp = 0; rp < RPT; ++rp)
        a4[rp] = *(const float4*)&sA[(rs * RPT + rp) * SAS + kq * 4];
      #pragma unroll
      for (int i = 0; i < 4; ++i) {
        float4 w4 = *(const float4*)&sW[(kq * 4 + i) * 64 + cq * 4];
        #pragma unroll
        for (int rp = 0; rp < RPT; ++rp) {
          float a = (i == 0) ? a4[rp].x : (i == 1) ? a4[rp].y
                  : (i == 2) ? a4[rp].z : a4[rp].w;
          acc[rp].x += a * w4.x; acc[rp].y += a * w4.y;
          acc[rp].z += a * w4.z; acc[rp].w += a * w4.w;
        }
      }
    }
    __syncthreads();
  }
  #pragma unroll
  for (int rp = 0; rp < RPT; ++rp) {
    int r = row0 + rs * RPT + rp;
    if constexpr (AL) {
      *(float4*)&out[(size_t)r * 64 + cq * 4] = acc[rp];   // raw h
      float4 s4 = *(const float4*)&a_s[cq * 4];
      float4 d4 = *(const float4*)&a_d[cq * 4];
      float vs = acc[rp].x * s4.x + acc[rp].y * s4.y + acc[rp].z * s4.z + acc[rp].w * s4.w;
      float vd = acc[rp].x * d4.x + acc[rp].y * d4.y + acc[rp].z * d4.z + acc[rp].w * d4.w;
      #pragma unroll
      for (int o = 8; o >= 1; o >>= 1) { vs += __shfl_xor(vs, o); vd += __shfl_xor(vd, o); }
      if (cq == 0) { als[r] = vs; ald[r] = vd; }
    } else {
      float4 b4 = *(const float4*)&bias[cq * 4];
      float4 v = acc[rp];
      v.x = fmaxf(v.x + b4.x, 0.f); v.y = fmaxf(v.y + b4.y, 0.f);
      v.z = fmaxf(v.z + b4.z, 0.f); v.w = fmaxf(v.w + b4.w, 0.f);
      *(float4*)&out[(size_t)r * 64 + cq * 4] = v;
    }
  }
}

// ---------------- fc1 split-K: part[sp][row][c] = A[row, sp*128:+128]·W[sp*128:+128, c]
__global__ __launch_bounds__(256) void gemm_fc1_split(
    const float* __restrict__ A, const float* __restrict__ W,
    float* __restrict__ part) {
  __shared__ float sW[128 * 64];     // 32 KB
  __shared__ float sA[16 * 132];     // 16 rows x 128 k, padded stride
  int t = threadIdx.x;
  int bid = blockIdx.x;
  int rt = bid >> 5;                 // row tile (0..127)
  int sp = bid & 31;                 // k-split  (0..31)
  #pragma unroll
  for (int j = 0; j < 8; ++j) {      // stage W chunk [128][64]
    int li = t + j * 256;
    int kk = li >> 4, cc = (li & 15) * 4;
    *(float4*)&sW[kk * 64 + cc] =
        *(const float4*)&W[(size_t)(sp * 128 + kk) * 64 + cc];
  }
  #pragma unroll
  for (int j = 0; j < 2; ++j) {      // stage A tile [16][128]
    int li = t + j * 256;
    int r = li >> 5, kq4 = (li & 31) * 4;
    *(float4*)&sA[r * 132 + kq4] =
        *(const float4*)&A[(size_t)(rt * 16 + r) * 4096 + sp * 128 + kq4];
  }
  __syncthreads();
  int cq = t & 15;                   // col quad
  int rs = t >> 4;                   // row slot (0..15)
  float4 acc = make_float4(0.f, 0.f, 0.f, 0.f);
  #pragma unroll
  for (int kq = 0; kq < 32; ++kq) {
    float4 a4 = *(const float4*)&sA[rs * 132 + kq * 4];
    #pragma unroll
    for (int i = 0; i < 4; ++i) {
      float4 w4 = *(const float4*)&sW[(kq * 4 + i) * 64 + cq * 4];
      float a = (i == 0) ? a4.x : (i == 1) ? a4.y : (i == 2) ? a4.z : a4.w;
      acc.x += a * w4.x; acc.y += a * w4.y; acc.z += a * w4.z; acc.w += a * w4.w;
    }
  }
  *(float4*)&part[((size_t)sp * BB + rt * 16 + rs) * 64 + cq * 4] = acc;
}

// ---------------- H=1 aggregate with precomputed weights + bias + relu
__global__ __launch_bounds__(256) void gat_aggregate(
    const float* __restrict__ hsrc, const float* __restrict__ warr,
    const int* __restrict__ offs, const int* __restrict__ esrc,
    const float* __restrict__ bias, float* __restrict__ out) {
  int wv = threadIdx.x >> 6;
  int lane = threadIdx.x & 63;
  int n = blockIdx.x * 4 + wv;
  int start = offs[n], end = offs[n + 1];
  float acc = 0.f, S = 0.f;
  int j = start;
  for (; j + 4 <= end; j += 4) {          // 4 gathers in flight
    int s0 = esrc[j], s1 = esrc[j+1], s2 = esrc[j+2], s3 = esrc[j+3];
    float w0 = warr[j], w1 = warr[j+1], w2 = warr[j+2], w3 = warr[j+3];
    float v0 = hsrc[(size_t)s0 * 64 + lane];
    float v1 = hsrc[(size_t)s1 * 64 + lane];
    float v2 = hsrc[(size_t)s2 * 64 + lane];
    float v3 = hsrc[(size_t)s3 * 64 + lane];
    acc += w0 * v0; acc += w1 * v1; acc += w2 * v2; acc += w3 * v3;
    S += w0 + w1 + w2 + w3;
  }
  for (; j < end; ++j) {
    int s = esrc[j]; float w = warr[j];
    acc += w * hsrc[(size_t)s * 64 + lane];
    S += w;
  }
  float v = acc / (S + 1e-16f) + bias[lane];
  out[(size_t)n * 64 + lane] = fmaxf(v, 0.f);
}

// ---------------- fused fc1-reduce + fc2 + fc3 + softmax, one wave per batch row
__global__ __launch_bounds__(256) void fc23_softmax(
    const float* __restrict__ part, const float* __restrict__ fcb1,
    const float* __restrict__ W2, const float* __restrict__ b2,
    const float* __restrict__ W3, const float* __restrict__ b3,
    float* __restrict__ out) {
  int ws = threadIdx.x >> 6;
  int row = blockIdx.x * 4 + ws;
  int lane = threadIdx.x & 63;
  __shared__ float sh1[4][64];
  __shared__ float sh2[4][32];
  // reduce the 32 k-split partials for h1[row][lane] (coalesced 256B per sp)
  float h1 = fcb1[lane];
  #pragma unroll
  for (int sp = 0; sp < KSPLIT; sp += 4) {
    float p0 = part[((size_t)(sp + 0) * BB + row) * 64 + lane];
    float p1 = part[((size_t)(sp + 1) * BB + row) * 64 + lane];
    float p2 = part[((size_t)(sp + 2) * BB + row) * 64 + lane];
    float p3 = part[((size_t)(sp + 3) * BB + row) * 64 + lane];
    h1 += p0 + p1 + p2 + p3;
  }
  sh1[ws][lane] = fmaxf(h1, 0.f);     // wave-local: no barrier
  if (lane < 32) {
    float acc = b2[lane];
    #pragma unroll
    for (int k = 0; k < 64; ++k) acc += sh1[ws][k] * W2[k * 32 + lane];
    sh2[ws][lane] = fmaxf(acc, 0.f);  // wave-local
  }
  float logit = -INFINITY;
  if (lane < 16) {
    float acc = b3[lane];
    #pragma unroll
    for (int k = 0; k < 32; ++k) acc += sh2[ws][k] * W3[k * 16 + lane];
    logit = acc;
  }
  float mx = logit;
  #pragma unroll
  for (int o = 8; o >= 1; o >>= 1) mx = fmaxf(mx, __shfl_xor(mx, o));
  float ex = (lane < 16) ? __expf(logit - mx) : 0.f;
  float ssum = ex;
  #pragma unroll
  for (int o = 8; o >= 1; o >>= 1) ssum += __shfl_xor(ssum, o);
  if (lane < 16) out[row * 16 + lane] = ex / ssum;
}

// ---------------- launcher ----------------
extern "C" void kernel_launch(void* const* d_in, const int* in_sizes, int n_in,
                              void* d_out, int out_size, void* d_ws, size_t ws_size,
                              hipStream_t stream) {
  const float* x0   = (const float*)d_in[0];
  const int*   ei   = (const int*)d_in[1];
  const float* W1   = (const float*)d_in[2];
  const float* a1s  = (const float*)d_in[3];
  const float* a1d  = (const float*)d_in[4];
  const float* b1   = (const float*)d_in[5];
  const float* W2   = (const float*)d_in[6];
  const float* a2s  = (const float*)d_in[7];
  const float* a2d  = (const float*)d_in[8];
  const float* b2   = (const float*)d_in[9];
  const float* W3   = (const float*)d_in[10];
  const float* a3s  = (const float*)d_in[11];
  const float* a3d  = (const float*)d_in[12];
  const float* b3   = (const float*)d_in[13];
  const float* fcW1 = (const float*)d_in[14];
  const float* fcb1 = (const float*)d_in[15];
  const float* fcW2 = (const float*)d_in[16];
  const float* fcb2 = (const float*)d_in[17];
  const float* fcW3 = (const float*)d_in[18];
  const float* fcb3 = (const float*)d_in[19];
  float* out = (float*)d_out;

  // workspace layout (~214 MB)
  float* agg1   = (float*)d_ws;                       // [N*256] scratch region (33.5M floats)
  float* h23    = agg1 + (size_t)NN * 256;            // [N*64]
  float* agg23  = h23 + (size_t)NN * 64;              // [N*64]
  float* als1   = agg23 + (size_t)NN * 64;            // [N*4]
  float* ald1   = als1 + (size_t)NN * 4;              // [N*4]
  float* als2   = ald1 + (size_t)NN * 4;              // [N]
  float* ald2   = als2 + NN;                          // [N]
  float* wts    = ald2 + NN;                          // [128]
  float* wtd    = wts + 128;                          // [128]
  int*   counts = (int*)(wtd + 128);                  // [N]
  int*   offs   = counts + NN;                        // [N+1]
  int*   cursor = offs + NN + 1;                      // [N]
  int*   esrc   = cursor + NN;                        // [ET]
  int*   edst   = esrc + ET;                          // [ET]
  int*   blksums= edst + ET;                          // [512]
  // overlays inside the agg1 scratch region (no agg1 tensor anymore):
  float4* w41   = (float4*)agg1;                      // [ET] f4 (0 .. 2.62M fl), dead after gat1_agg
  float* h2     = agg1 + ((size_t)4 << 20);           // [N*64] (4M .. 12.4M fl)
  float* als3   = agg1 + ((size_t)13 << 20);          // [N]
  float* ald3   = als3 + NN;                          // [N]
  float* w2     = agg1 + ((size_t)14 << 20);          // [ET]
  float* w3arr  = w2 + ET;                            // [ET]
  float* part   = agg1 + ((size_t)16 << 20);          // [KSPLIT*B*64] = 4.2M fl
  float* ya     = h23;                                // [N*128] spans h23+agg23 (dead after gat2_fused)

  // CSR build (reused by all 3 GAT layers)
  init_counts<<<NN / 256, 256, 0, stream>>>(counts);
  count_edges<<<EE / 256, 256, 0, stream>>>(ei, counts);
  scan_block<<<NN / 256, 256, 0, stream>>>(counts, offs, blksums);
  scan_sums<<<1, 512, 0, stream>>>(blksums);
  scan_add<<<NN / 256, 256, 0, stream>>>(offs, cursor, blksums);
  fill_csr<<<ET / 256, 256, 0, stream>>>(ei, cursor, esrc, edst);

  // GAT1: logits via tiny projections; per-edge weights; pure aggregate
  l1_avec<<<1, 128, 0, stream>>>(W1, a1s, a1d, wts, wtd);
  l1_logits<<<NN / 64, 256, 0, stream>>>(x0, wts, wtd, als1, ald1);
  edge_w4<<<ET / 256, 256, 0, stream>>>(esrc, edst, als1, ald1, w41);
  gat1_agg<<<NN / 4, 256, 0, stream>>>(x0, offs, esrc, w41, ya);
  // fused GAT1-proj + GAT2-GEMM: ya -> h2 + als2/ald2 (agg1 never materialized)
  gat2_fused<<<NN / 64, 256, 0, stream>>>(ya, W1, b1, W2, a2s, a2d, h2, als2, ald2);
  edge_w1<<<ET / 256, 256, 0, stream>>>(esrc, edst, als2, ald2, w2);
  // GAT2 aggregate -> agg2 (bias+relu)
  gat_aggregate<<<NN / 4, 256, 0, stream>>>(h2, w2, offs, esrc, b2, agg23);
  // GAT3 GEMM: [N,64]@[64,64] -> h3 + als3/ald3
  gemm_n64<1, 64, true><<<NN / 64, 256, 0, stream>>>(agg23, W3, nullptr, a3s, a3d, h23, als3, ald3);
  edge_w1<<<ET / 256, 256, 0, stream>>>(esrc, edst, als3, ald3, w3arr);
  // GAT3 aggregate -> agg3
  gat_aggregate<<<NN / 4, 256, 0, stream>>>(h23, w3arr, offs, esrc, b3, agg23);
  // actor MLP: split-K fc1 partials, then fused reduce+fc2+fc3+softmax
  gemm_fc1_split<<<128 * KSPLIT, 256, 0, stream>>>(agg23, fcW1, part);
  fc23_softmax<<<BB / 4, 256, 0, stream>>>(part, fcb1, fcW2, fcb2, fcW3, fcb3, out);
}